// Round 6
// baseline (190.907 us; speedup 1.0000x reference)
//
#include <hip/hip_runtime.h>
#include <stdint.h>

#define BDIM 4
#define CDIM 512
#define HDIM 128
#define WDIM 128
#define HWDIM (HDIM*WDIM)
#define SADMP 16
#define BHW 8
#define KKP 256

using short8  = __attribute__((ext_vector_type(8))) short;
using f32x16  = __attribute__((ext_vector_type(16))) float;

__device__ __forceinline__ unsigned short f2bf(float f) {
    unsigned u = __float_as_uint(f);
    unsigned r = (u + 0x7fffu + ((u >> 16) & 1u)) >> 16;
    return (unsigned short)r;
}
__device__ __forceinline__ float bf2f(unsigned short h) {
    return __uint_as_float(((unsigned)h) << 16);
}
__device__ __forceinline__ unsigned int ordf(float f) {
    unsigned u = __float_as_uint(f);
    return (u & 0x80000000u) ? ~u : (u | 0x80000000u);
}

// ---------------- K1: resp[b][hw] = sum_c A[b][c][hw] ----------------
__global__ void resp_kernel(const float* __restrict__ A, float* __restrict__ resp) {
    int gid = blockIdx.x * blockDim.x + threadIdx.x;
    int b = gid / HWDIM, hw = gid % HWDIM;
    const float* p = A + (size_t)b * CDIM * HWDIM + hw;
    float s0 = 0.f, s1 = 0.f, s2 = 0.f, s3 = 0.f;
    #pragma unroll 4
    for (int c = 0; c < CDIM; c += 4) {
        s0 += p[(size_t)(c + 0) * HWDIM];
        s1 += p[(size_t)(c + 1) * HWDIM];
        s2 += p[(size_t)(c + 2) * HWDIM];
        s3 += p[(size_t)(c + 3) * HWDIM];
    }
    resp[gid] = (s0 + s1) + (s2 + s3);
}

// ---------------- K2: per-window argmax (first occurrence) ----------------
__global__ void argmax_kernel(const float* __restrict__ resp, int* __restrict__ kp) {
    int win = blockIdx.x;                 // b*K + k
    int b = win / KKP, k = win % KKP;
    int bi = k / SADMP, bj = k % SADMP;
    int l = threadIdx.x;                  // 0..63 == loc
    int r = l >> 3, c = l & 7;
    int h = bi * BHW + r, w = bj * BHW + c;
    float v = resp[b * HWDIM + h * WDIM + w];
    int idx = l;
    #pragma unroll
    for (int off = 32; off; off >>= 1) {
        float ov = __shfl_down(v, off);
        int   oi = __shfl_down(idx, off);
        if (ov > v || (ov == v && oi < idx)) { v = ov; idx = oi; }
    }
    if (l == 0) {
        int row = bi * BHW + (idx >> 3);
        int col = bj * BHW + (idx & 7);
        kp[win] = row * WDIM + col;
    }
}

// ---------------- K3: gather + hi/lo convert into 32x32 MFMA A-operand order + dn ----
// frag layout (uint4 units): b*32768 + term*16384 + (rt*32 + q)*64 + slot
//   lane/slot s holds A[m = rt*32 + (s&31)][k = q*16 + (s>>5)*8 + j], j=0..7
__global__ void convert_kernel(const float* __restrict__ A, const int* __restrict__ kp,
                               uint4* __restrict__ frag, float* __restrict__ dn) {
    int blk = blockIdx.x;                 // b*8 + rt
    int b = blk >> 3, rt = blk & 7;
    int t = threadIdx.x;                  // 0..255
    int ml = t & 31, cgrp = t >> 5;       // row-in-tile, channel group (64 ch each)
    int m = rt * 32 + ml;
    int idx = kp[b * KKP + m];
    const float* Ab = A + (size_t)b * CDIM * HWDIM + idx;
    float sq = 0.f;
    #pragma unroll
    for (int j = 0; j < 8; j++) {         // chunks of 8 channels
        int c0 = cgrp * 64 + j * 8;
        int q = c0 >> 4;                  // k-slice of 16
        int slot = ((j & 1) << 5) + ml;
        unsigned hi[4], lo[4];
        #pragma unroll
        for (int p = 0; p < 4; p++) {
            float v0 = Ab[(size_t)(c0 + 2 * p) * HWDIM];
            float v1 = Ab[(size_t)(c0 + 2 * p + 1) * HWDIM];
            sq = fmaf(v0, v0, sq);
            sq = fmaf(v1, v1, sq);
            unsigned short h0 = f2bf(v0), h1 = f2bf(v1);
            unsigned short g0 = f2bf(v0 - bf2f(h0)), g1 = f2bf(v1 - bf2f(h1));
            hi[p] = (unsigned)h0 | ((unsigned)h1 << 16);
            lo[p] = (unsigned)g0 | ((unsigned)g1 << 16);
        }
        frag[(size_t)b * 32768 +         (rt * 32 + q) * 64 + slot] = make_uint4(hi[0], hi[1], hi[2], hi[3]);
        frag[(size_t)b * 32768 + 16384 + (rt * 32 + q) * 64 + slot] = make_uint4(lo[0], lo[1], lo[2], lo[3]);
    }
    __shared__ float red[32][9];
    red[ml][cgrp] = sq;
    __syncthreads();
    if (t < 32) {
        float ssum = 0.f;
        #pragma unroll
        for (int i = 0; i < 8; i++) ssum += red[t][i];
        dn[b * KKP + rt * 32 + t] = ssum;
    }
}

// ---------------- K4: MFMA dist + argmin — BARRIER-FREE, register-B ----------------
// Each wave: BM=128 (4 row-tiles), BN=64 (2 col-groups of 32), K=512.
// B operand loaded straight from global into fragment registers (lane s holds
// B[k=(s>>5)*8+j][n=s&31]) and converted hi/lo in-reg. No LDS, no __syncthreads:
// nothing ever forces a vmcnt drain, compiler pipelines loads across MFMAs.
__global__ __launch_bounds__(256, 2) void dist_mfma_kernel(
    const uint4* __restrict__ fragA, const float* __restrict__ fb,
    const float* __restrict__ dn, unsigned long long* __restrict__ minkey)
{
    const int t  = threadIdx.x;
    const int l  = t & 63;
    const int w  = t >> 6;                // 4 waves: {2 row-halves} x {2 n-tiles}
    const int b  = blockIdx.y;
    const int rh = w & 1;                 // row half: rows rh*128 .. rh*128+127
    const int n0 = (blockIdx.x * 2 + (w >> 1)) * 64;
    const int lh = l >> 5, ln = l & 31;

    f32x16 acc[4][2] = {};                // [rt][cg]
    float bn0 = 0.f, bn1 = 0.f;

    const float* fb0 = fb + (size_t)b * CDIM * HWDIM + (size_t)(lh * 8) * HWDIM + n0 + ln;
    const float* fb1 = fb0 + 32;
    const uint4* fA  = fragA + (size_t)b * 32768 + l;

    #pragma unroll 2
    for (int q = 0; q < 32; q++) {
        // B fragment loads (8 strided floats per cg per lane)
        float v0[8], v1[8];
        #pragma unroll
        for (int j = 0; j < 8; j++) {
            v0[j] = fb0[(size_t)(q * 16 + j) * HWDIM];
            v1[j] = fb1[(size_t)(q * 16 + j) * HWDIM];
        }
        // in-register hi/lo convert + bn accumulate
        unsigned h0w[4], l0w[4], h1w[4], l1w[4];
        #pragma unroll
        for (int p = 0; p < 4; p++) {
            float a0 = v0[2 * p], a1 = v0[2 * p + 1];
            float c0 = v1[2 * p], c1 = v1[2 * p + 1];
            bn0 = fmaf(a0, a0, bn0); bn0 = fmaf(a1, a1, bn0);
            bn1 = fmaf(c0, c0, bn1); bn1 = fmaf(c1, c1, bn1);
            unsigned short ha0 = f2bf(a0), ha1 = f2bf(a1);
            unsigned short ga0 = f2bf(a0 - bf2f(ha0)), ga1 = f2bf(a1 - bf2f(ha1));
            unsigned short hc0 = f2bf(c0), hc1 = f2bf(c1);
            unsigned short gc0 = f2bf(c0 - bf2f(hc0)), gc1 = f2bf(c1 - bf2f(hc1));
            h0w[p] = (unsigned)ha0 | ((unsigned)ha1 << 16);
            l0w[p] = (unsigned)ga0 | ((unsigned)ga1 << 16);
            h1w[p] = (unsigned)hc0 | ((unsigned)hc1 << 16);
            l1w[p] = (unsigned)gc0 | ((unsigned)gc1 << 16);
        }
        uint4 uh0 = make_uint4(h0w[0], h0w[1], h0w[2], h0w[3]);
        uint4 ul0 = make_uint4(l0w[0], l0w[1], l0w[2], l0w[3]);
        uint4 uh1 = make_uint4(h1w[0], h1w[1], h1w[2], h1w[3]);
        uint4 ul1 = make_uint4(l1w[0], l1w[1], l1w[2], l1w[3]);
        short8 bh0 = *(short8*)&uh0, bl0 = *(short8*)&ul0;
        short8 bh1 = *(short8*)&uh1, bl1 = *(short8*)&ul1;

        #pragma unroll
        for (int rt = 0; rt < 4; rt++) {
            const int RT = rh * 4 + rt;
            uint4 uah = fA[        (size_t)(RT * 32 + q) * 64];
            uint4 ual = fA[16384 + (size_t)(RT * 32 + q) * 64];
            short8 ah = *(short8*)&uah, al = *(short8*)&ual;
            acc[rt][0] = __builtin_amdgcn_mfma_f32_32x32x16_bf16(ah, bh0, acc[rt][0], 0, 0, 0);
            acc[rt][0] = __builtin_amdgcn_mfma_f32_32x32x16_bf16(ah, bl0, acc[rt][0], 0, 0, 0);
            acc[rt][0] = __builtin_amdgcn_mfma_f32_32x32x16_bf16(al, bh0, acc[rt][0], 0, 0, 0);
            acc[rt][1] = __builtin_amdgcn_mfma_f32_32x32x16_bf16(ah, bh1, acc[rt][1], 0, 0, 0);
            acc[rt][1] = __builtin_amdgcn_mfma_f32_32x32x16_bf16(ah, bl1, acc[rt][1], 0, 0, 0);
            acc[rt][1] = __builtin_amdgcn_mfma_f32_32x32x16_bf16(al, bh1, acc[rt][1], 0, 0, 0);
        }
    }

    // bn finalize: lane l and l^32 hold complementary channel halves of same col
    bn0 += __shfl_xor(bn0, 32);
    bn1 += __shfl_xor(bn1, 32);

    // epilogue: dist = dn - 2*cross + bn; per-m packed argmin over 32 cols x 2 cgs
    #pragma unroll
    for (int rt = 0; rt < 4; rt++) {
        #pragma unroll
        for (int r = 0; r < 16; r++) {
            int m = rh * 128 + rt * 32 + (r & 3) + 8 * (r >> 2) + 4 * lh;
            float dnm = dn[b * KKP + m];
            float d0 = dnm - 2.f * acc[rt][0][r] + bn0;
            float d1 = dnm - 2.f * acc[rt][1][r] + bn1;
            unsigned long long k0 = ((unsigned long long)ordf(d0) << 32) | (unsigned)(n0 + ln);
            unsigned long long k1 = ((unsigned long long)ordf(d1) << 32) | (unsigned)(n0 + 32 + ln);
            unsigned long long best = k0 < k1 ? k0 : k1;
            #pragma unroll
            for (int off = 1; off < 32; off <<= 1) {
                unsigned long long o = __shfl_xor(best, off);
                if (o < best) best = o;
            }
            if (ln == 0) atomicMin(&minkey[b * KKP + m], best);
        }
    }
}

// ---------------- K5: finalize ----------------
__global__ void finalize_kernel(const unsigned long long* __restrict__ minkey,
                                const int* __restrict__ kp,
                                float* __restrict__ out)
{
    int b = blockIdx.x;
    int k = threadIdx.x;
    unsigned long long key = minkey[b * KKP + k];
    unsigned n   = (unsigned)(key & 0xffffffffu);
    unsigned top = (unsigned)(key >> 32);
    unsigned fbits = (top & 0x80000000u) ? (top ^ 0x80000000u) : ~top;
    out[8 + b * KKP + k] = __uint_as_float(fbits);

    int idxA = kp[b * KKP + k];
    int rowA = idxA >> 7, colA = idxA & 127;
    int rowB = (int)(n >> 7), colB = (int)(n & 127);
    int drow = rowA - rowB, dcol = colA - colB;
    int code = (drow + 256) * 1024 + (dcol + 256);

    __shared__ int codes[KKP];
    __shared__ int keys[KKP];
    codes[k] = code;
    __syncthreads();
    int cnt = 0;
    for (int j = 0; j < KKP; j++) cnt += (codes[j] == code);
    keys[k] = cnt * 256 + (255 - k);
    __syncthreads();
    for (int s = 128; s; s >>= 1) {
        if (k < s) keys[k] = max(keys[k], keys[k + s]);
        __syncthreads();
    }
    if (k == 0) {
        int bestk = 255 - (keys[0] & 255);
        int bc = codes[bestk];
        int dr = bc / 1024 - 256, dc = bc % 1024 - 256;
        out[b * 2 + 0] = (float)dr;
        out[b * 2 + 1] = (float)dc;
    }
}

extern "C" void kernel_launch(void* const* d_in, const int* in_sizes, int n_in,
                              void* d_out, int out_size, void* d_ws, size_t ws_size,
                              hipStream_t stream) {
    const float* A  = (const float*)d_in[0];
    const float* Bf = (const float*)d_in[1];
    float* out = (float*)d_out;
    char* ws = (char*)d_ws;

    float* resp = (float*)ws;                                   // 256 KB
    int*   kp   = (int*)(ws + 262144);                          // 4 KB
    float* dn   = (float*)(ws + 266240);                        // 4 KB
    unsigned long long* minkey = (unsigned long long*)(ws + 270336); // 8 KB
    uint4* frag = (uint4*)(ws + 278528);                        // 2 MB

    hipMemsetAsync(minkey, 0xFF, BDIM * KKP * sizeof(unsigned long long), stream);
    resp_kernel<<<BDIM * HWDIM / 256, 256, 0, stream>>>(A, resp);
    argmax_kernel<<<BDIM * KKP, 64, 0, stream>>>(resp, kp);
    convert_kernel<<<BDIM * 8, 256, 0, stream>>>(A, kp, frag, dn);
    dist_mfma_kernel<<<dim3(128, BDIM), 256, 0, stream>>>(frag, Bf, dn, minkey);
    finalize_kernel<<<BDIM, KKP, 0, stream>>>(minkey, kp, out);
}

// Round 7
// 140.495 us; speedup vs baseline: 1.3588x; 1.3588x over previous
//
#include <hip/hip_runtime.h>
#include <stdint.h>

#define BDIM 4
#define CDIM 512
#define HDIM 128
#define WDIM 128
#define HWDIM (HDIM*WDIM)
#define SADMP 16
#define BHW 8
#define KKP 256

using short8 = __attribute__((ext_vector_type(8))) short;
using f32x4  = __attribute__((ext_vector_type(4))) float;

__device__ __forceinline__ unsigned short f2bf(float f) {
    unsigned u = __float_as_uint(f);
    unsigned r = (u + 0x7fffu + ((u >> 16) & 1u)) >> 16;
    return (unsigned short)r;
}
__device__ __forceinline__ float bf2f(unsigned short h) {
    return __uint_as_float(((unsigned)h) << 16);
}
__device__ __forceinline__ unsigned int ordf(float f) {
    unsigned u = __float_as_uint(f);
    return (u & 0x80000000u) ? ~u : (u | 0x80000000u);
}
// writer-side LDS drain + raw barrier (m201 discipline; rule-18 sched fence)
__device__ __forceinline__ void step_barrier() {
    asm volatile("s_waitcnt lgkmcnt(0)" ::: "memory");
    __builtin_amdgcn_sched_barrier(0);
    __builtin_amdgcn_s_barrier();
}

// ---------------- K1a: channel-chunk partial sums (8 chunks of 64) ----------------
__global__ void resp_part_kernel(const float* __restrict__ A, float* __restrict__ part) {
    int gid = blockIdx.x * blockDim.x + threadIdx.x;   // (b*8+cq)*HW + hw
    int hw = gid & (HWDIM - 1);
    int rest = gid >> 14;
    int b = rest >> 3, cq = rest & 7;
    const float* p = A + (size_t)b * CDIM * HWDIM + (size_t)(cq * 64) * HWDIM + hw;
    float s0 = 0.f, s1 = 0.f, s2 = 0.f, s3 = 0.f;
    #pragma unroll 4
    for (int c = 0; c < 64; c += 4) {
        s0 += p[(size_t)(c + 0) * HWDIM];
        s1 += p[(size_t)(c + 1) * HWDIM];
        s2 += p[(size_t)(c + 2) * HWDIM];
        s3 += p[(size_t)(c + 3) * HWDIM];
    }
    part[gid] = (s0 + s1) + (s2 + s3);
}
// ---------------- K1b: combine (ascending cq -> deterministic) ----------------
__global__ void resp_comb_kernel(const float* __restrict__ part, float* __restrict__ resp) {
    int gid = blockIdx.x * blockDim.x + threadIdx.x;   // b*HW + hw
    int hw = gid & (HWDIM - 1);
    int b = gid >> 14;
    const float* p = part + (size_t)(b * 8) * HWDIM + hw;
    float s = 0.f;
    #pragma unroll
    for (int cq = 0; cq < 8; cq++) s += p[(size_t)cq * HWDIM];
    resp[gid] = s;
}

// ---------------- K2: per-window argmax (first occurrence) ----------------
__global__ void argmax_kernel(const float* __restrict__ resp, int* __restrict__ kp) {
    int win = blockIdx.x;                 // b*K + k
    int b = win / KKP, k = win % KKP;
    int bi = k / SADMP, bj = k % SADMP;
    int l = threadIdx.x;                  // 0..63 == loc
    int r = l >> 3, c = l & 7;
    int h = bi * BHW + r, w = bj * BHW + c;
    float v = resp[b * HWDIM + h * WDIM + w];
    int idx = l;
    #pragma unroll
    for (int off = 32; off; off >>= 1) {
        float ov = __shfl_down(v, off);
        int   oi = __shfl_down(idx, off);
        if (ov > v || (ov == v && oi < idx)) { v = ov; idx = oi; }
    }
    if (l == 0) {
        int row = bi * BHW + (idx >> 3);
        int col = bj * BHW + (idx & 7);
        kp[win] = row * WDIM + col;
    }
}

// ---------------- K3: gather + hi/lo convert into 16x16 MFMA A-frag order + dn ----
// frag (uint4): (b*2+term)*16384 + mf*1024 + q*64 + lane
//   lane holds A[m=mf*16+(lane&15)][c=q*32+(lane>>4)*8+j]
__global__ void convert_kernel(const float* __restrict__ A, const int* __restrict__ kp,
                               uint4* __restrict__ frag, float* __restrict__ dn) {
    int blk = blockIdx.x;                 // b*16 + mf
    int b = blk >> 4, mf = blk & 15;
    int t = threadIdx.x;                  // 0..255
    int l = t & 63, q0 = t >> 6;
    int ml = l & 15;
    int m  = mf * 16 + ml;
    int cg = (l >> 4) * 8;
    int idx = kp[b * KKP + m];
    const float* Ab = A + (size_t)b * CDIM * HWDIM + idx;
    float sq = 0.f;
    #pragma unroll
    for (int qq = 0; qq < 4; qq++) {
        int q = q0 * 4 + qq;
        unsigned hi[4], lo[4];
        #pragma unroll
        for (int jj = 0; jj < 4; jj++) {
            int c0 = q * 32 + cg + jj * 2;
            float v0 = Ab[(size_t)c0 * HWDIM];
            float v1 = Ab[(size_t)(c0 + 1) * HWDIM];
            sq = fmaf(v0, v0, sq);
            sq = fmaf(v1, v1, sq);
            unsigned short h0 = f2bf(v0), h1 = f2bf(v1);
            unsigned short g0 = f2bf(v0 - bf2f(h0)), g1 = f2bf(v1 - bf2f(h1));
            hi[jj] = (unsigned)h0 | ((unsigned)h1 << 16);
            lo[jj] = (unsigned)g0 | ((unsigned)g1 << 16);
        }
        frag[((size_t)b * 2 + 0) * 16384 + mf * 1024 + q * 64 + l] = make_uint4(hi[0], hi[1], hi[2], hi[3]);
        frag[((size_t)b * 2 + 1) * 16384 + mf * 1024 + q * 64 + l] = make_uint4(lo[0], lo[1], lo[2], lo[3]);
    }
    __shared__ float red[16][17];
    red[ml][(l >> 4) * 4 + q0] = sq;
    __syncthreads();
    if (t < 16) {
        float s = 0.f;
        #pragma unroll
        for (int i = 0; i < 16; i++) s += red[t][i];
        dn[b * KKP + mf * 16 + t] = s;
    }
}

// ---------------- K4: MFMA dist + argmin ----------------
// BM=256, BN=64, BK=64/step, 8 steps, 16x16x32, bf16 hi/lo 3-term.
// Double-buffered fragment-order LDS ([term:2][ch:2][nf:4][1KB], contiguous
// 16B/lane writes+reads -> uniform-8, 0 conflicts). ONE raw s_barrier per step
// with writer-side lgkmcnt(0): fb prefetch for step s+1 stays in flight across
// the barrier (no vmcnt(0) drain in the loop). Convert VALU sits between the
// two MFMA ch-phases.
__global__ __launch_bounds__(512) void dist_mfma_kernel(
    const uint4* __restrict__ fragA, const float* __restrict__ fb,
    const float* __restrict__ dn, unsigned long long* __restrict__ minkey)
{
    const int n0 = blockIdx.x * 64;
    const int b  = blockIdx.y;
    const int t  = threadIdx.x;
    const int l  = t & 63;
    const int w  = t >> 6;                // wave 0..7: rows w*32 .. w*32+31

    __shared__ char sb[2][16384];         // [buf][term:2][ch:2][nf:4][1024]
    __shared__ float bnp[8][64];
    __shared__ float bnf[64];
    __shared__ float dnl[256];

    if (t < 256) dnl[t] = dn[b * KKP + t];

    f32x4 acc[2][4] = {};                 // [mfl][nf]

    // staging map: thread (scol=t&63, sw=t>>6) stages channels sw*8..+7 of col n0+scol
    const int scol = t & 63;
    const int sw   = t >> 6;
    // frag slot: ch=sw>>2, nf=scol>>4, slot=((sw&3)<<4)+(scol&15)
    const int wbase = ((sw >> 2) << 12) + ((scol >> 4) << 10) + (((((sw & 3) << 4) + (scol & 15))) << 4);
    const float* fbp = fb + (size_t)b * CDIM * HWDIM + (size_t)(sw * 8) * HWDIM + n0 + scol;
    float bnacc = 0.f;

    const short8* fA = (const short8*)fragA;
    const size_t baseHi = ((size_t)b * 2 + 0) * 16384;
    const size_t baseLo = ((size_t)b * 2 + 1) * 16384;

    float v[8];
    // prologue: load step0, convert+write buf0, issue step1 loads, barrier
    #pragma unroll
    for (int i = 0; i < 8; i++) v[i] = fbp[(size_t)i * HWDIM];
    {
        unsigned hi[4], lo[4];
        #pragma unroll
        for (int jj = 0; jj < 4; jj++) {
            float v0 = v[jj * 2], v1 = v[jj * 2 + 1];
            bnacc = fmaf(v0, v0, bnacc);
            bnacc = fmaf(v1, v1, bnacc);
            unsigned short h0 = f2bf(v0), h1 = f2bf(v1);
            unsigned short g0 = f2bf(v0 - bf2f(h0)), g1 = f2bf(v1 - bf2f(h1));
            hi[jj] = (unsigned)h0 | ((unsigned)h1 << 16);
            lo[jj] = (unsigned)g0 | ((unsigned)g1 << 16);
        }
        *(uint4*)(&sb[0][wbase])        = make_uint4(hi[0], hi[1], hi[2], hi[3]);
        *(uint4*)(&sb[0][wbase + 8192]) = make_uint4(lo[0], lo[1], lo[2], lo[3]);
    }
    #pragma unroll
    for (int i = 0; i < 8; i++) v[i] = fbp[(size_t)(64 + i) * HWDIM];
    step_barrier();

    for (int s = 0; s < 8; s++) {
        const int cur = s & 1;
        const char* rb = sb[cur];

        // ---- phase A: ch0 MFMAs
        {
            const int q = s * 2;
            short8 ah0 = fA[baseHi + (size_t)(w * 2 + 0) * 1024 + q * 64 + l];
            short8 ah1 = fA[baseHi + (size_t)(w * 2 + 1) * 1024 + q * 64 + l];
            short8 al0 = fA[baseLo + (size_t)(w * 2 + 0) * 1024 + q * 64 + l];
            short8 al1 = fA[baseLo + (size_t)(w * 2 + 1) * 1024 + q * 64 + l];
            const char* rp = rb + l * 16;
            #pragma unroll
            for (int nf = 0; nf < 4; nf++) {
                short8 bh = *(const short8*)(rp + nf * 1024);
                short8 bl = *(const short8*)(rp + nf * 1024 + 8192);
                acc[0][nf] = __builtin_amdgcn_mfma_f32_16x16x32_bf16(ah0, bh, acc[0][nf], 0, 0, 0);
                acc[0][nf] = __builtin_amdgcn_mfma_f32_16x16x32_bf16(ah0, bl, acc[0][nf], 0, 0, 0);
                acc[0][nf] = __builtin_amdgcn_mfma_f32_16x16x32_bf16(al0, bh, acc[0][nf], 0, 0, 0);
                acc[1][nf] = __builtin_amdgcn_mfma_f32_16x16x32_bf16(ah1, bh, acc[1][nf], 0, 0, 0);
                acc[1][nf] = __builtin_amdgcn_mfma_f32_16x16x32_bf16(ah1, bl, acc[1][nf], 0, 0, 0);
                acc[1][nf] = __builtin_amdgcn_mfma_f32_16x16x32_bf16(al1, bh, acc[1][nf], 0, 0, 0);
            }
        }

        // ---- staging: convert step s+1 (v in flight -> counted vmcnt) to buf^1
        if (s < 7) {
            unsigned hi[4], lo[4];
            #pragma unroll
            for (int jj = 0; jj < 4; jj++) {
                float v0 = v[jj * 2], v1 = v[jj * 2 + 1];
                bnacc = fmaf(v0, v0, bnacc);
                bnacc = fmaf(v1, v1, bnacc);
                unsigned short h0 = f2bf(v0), h1 = f2bf(v1);
                unsigned short g0 = f2bf(v0 - bf2f(h0)), g1 = f2bf(v1 - bf2f(h1));
                hi[jj] = (unsigned)h0 | ((unsigned)h1 << 16);
                lo[jj] = (unsigned)g0 | ((unsigned)g1 << 16);
            }
            char* wp = (char*)sb[cur ^ 1] + wbase;
            *(uint4*)(wp)        = make_uint4(hi[0], hi[1], hi[2], hi[3]);
            *(uint4*)(wp + 8192) = make_uint4(lo[0], lo[1], lo[2], lo[3]);
            // issue step s+2 loads (stay in flight across the barrier)
            if (s < 6) {
                #pragma unroll
                for (int i = 0; i < 8; i++)
                    v[i] = fbp[(size_t)((s + 2) * 64 + i) * HWDIM];
            }
        }

        // ---- phase B: ch1 MFMAs
        {
            const int q = s * 2 + 1;
            short8 ah0 = fA[baseHi + (size_t)(w * 2 + 0) * 1024 + q * 64 + l];
            short8 ah1 = fA[baseHi + (size_t)(w * 2 + 1) * 1024 + q * 64 + l];
            short8 al0 = fA[baseLo + (size_t)(w * 2 + 0) * 1024 + q * 64 + l];
            short8 al1 = fA[baseLo + (size_t)(w * 2 + 1) * 1024 + q * 64 + l];
            const char* rp = rb + 4096 + l * 16;
            #pragma unroll
            for (int nf = 0; nf < 4; nf++) {
                short8 bh = *(const short8*)(rp + nf * 1024);
                short8 bl = *(const short8*)(rp + nf * 1024 + 8192);
                acc[0][nf] = __builtin_amdgcn_mfma_f32_16x16x32_bf16(ah0, bh, acc[0][nf], 0, 0, 0);
                acc[0][nf] = __builtin_amdgcn_mfma_f32_16x16x32_bf16(ah0, bl, acc[0][nf], 0, 0, 0);
                acc[0][nf] = __builtin_amdgcn_mfma_f32_16x16x32_bf16(al0, bh, acc[0][nf], 0, 0, 0);
                acc[1][nf] = __builtin_amdgcn_mfma_f32_16x16x32_bf16(ah1, bh, acc[1][nf], 0, 0, 0);
                acc[1][nf] = __builtin_amdgcn_mfma_f32_16x16x32_bf16(ah1, bl, acc[1][nf], 0, 0, 0);
                acc[1][nf] = __builtin_amdgcn_mfma_f32_16x16x32_bf16(al1, bh, acc[1][nf], 0, 0, 0);
            }
        }

        if (s < 7) step_barrier();
    }

    // bn reduction
    bnp[sw][scol] = bnacc;
    __syncthreads();
    if (t < 64) {
        float s = 0.f;
        #pragma unroll
        for (int i = 0; i < 8; i++) s += bnp[i][t];
        bnf[t] = s;
    }
    __syncthreads();

    // epilogue: dist = dn - 2*cross + bn, packed argmin, atomicMin
    #pragma unroll
    for (int mfl = 0; mfl < 2; mfl++) {
        #pragma unroll
        for (int r = 0; r < 4; r++) {
            int m = w * 32 + mfl * 16 + (l >> 4) * 4 + r;
            float dnm = dnl[m];
            unsigned long long best = ~0ull;
            #pragma unroll
            for (int nf = 0; nf < 4; nf++) {
                int nloc = nf * 16 + (l & 15);
                float d = dnm - 2.f * acc[mfl][nf][r] + bnf[nloc];
                unsigned long long key = ((unsigned long long)ordf(d) << 32) | (unsigned)(n0 + nloc);
                if (key < best) best = key;
            }
            #pragma unroll
            for (int off = 1; off < 16; off <<= 1) {
                unsigned long long o = __shfl_xor(best, off);
                if (o < best) best = o;
            }
            if ((l & 15) == 0) atomicMin(&minkey[b * KKP + m], best);
        }
    }
}

// ---------------- K5: finalize ----------------
__global__ void finalize_kernel(const unsigned long long* __restrict__ minkey,
                                const int* __restrict__ kp,
                                float* __restrict__ out)
{
    int b = blockIdx.x;
    int k = threadIdx.x;
    unsigned long long key = minkey[b * KKP + k];
    unsigned n   = (unsigned)(key & 0xffffffffu);
    unsigned top = (unsigned)(key >> 32);
    unsigned fbits = (top & 0x80000000u) ? (top ^ 0x80000000u) : ~top;
    out[8 + b * KKP + k] = __uint_as_float(fbits);

    int idxA = kp[b * KKP + k];
    int rowA = idxA >> 7, colA = idxA & 127;
    int rowB = (int)(n >> 7), colB = (int)(n & 127);
    int drow = rowA - rowB, dcol = colA - colB;
    int code = (drow + 256) * 1024 + (dcol + 256);

    __shared__ int codes[KKP];
    __shared__ int keys[KKP];
    codes[k] = code;
    __syncthreads();
    int cnt = 0;
    for (int j = 0; j < KKP; j++) cnt += (codes[j] == code);
    keys[k] = cnt * 256 + (255 - k);
    __syncthreads();
    for (int s = 128; s; s >>= 1) {
        if (k < s) keys[k] = max(keys[k], keys[k + s]);
        __syncthreads();
    }
    if (k == 0) {
        int bestk = 255 - (keys[0] & 255);
        int bc = codes[bestk];
        int dr = bc / 1024 - 256, dc = bc % 1024 - 256;
        out[b * 2 + 0] = (float)dr;
        out[b * 2 + 1] = (float)dc;
    }
}

extern "C" void kernel_launch(void* const* d_in, const int* in_sizes, int n_in,
                              void* d_out, int out_size, void* d_ws, size_t ws_size,
                              hipStream_t stream) {
    const float* A  = (const float*)d_in[0];
    const float* Bf = (const float*)d_in[1];
    float* out = (float*)d_out;
    char* ws = (char*)d_ws;

    float* resp = (float*)ws;                                   // 256 KB
    int*   kp   = (int*)(ws + 262144);                          // 4 KB
    float* dn   = (float*)(ws + 266240);                        // 4 KB
    unsigned long long* minkey = (unsigned long long*)(ws + 270336); // 8 KB
    uint4* frag = (uint4*)(ws + 278528);                        // 2 MB
    float* part = (float*)(ws + 278528 + 2097152);              // 2 MB

    hipMemsetAsync(minkey, 0xFF, BDIM * KKP * sizeof(unsigned long long), stream);
    resp_part_kernel<<<BDIM * 8 * HWDIM / 256, 256, 0, stream>>>(A, part);
    resp_comb_kernel<<<BDIM * HWDIM / 256, 256, 0, stream>>>(part, resp);
    argmax_kernel<<<BDIM * KKP, 64, 0, stream>>>(resp, kp);
    convert_kernel<<<BDIM * 16, 256, 0, stream>>>(A, kp, frag, dn);
    dist_mfma_kernel<<<dim3(256, BDIM), 512, 0, stream>>>(frag, Bf, dn, minkey);
    finalize_kernel<<<BDIM, KKP, 0, stream>>>(minkey, kp, out);
}

// Round 8
// 135.987 us; speedup vs baseline: 1.4039x; 1.0332x over previous
//
#include <hip/hip_runtime.h>
#include <stdint.h>

#define BDIM 4
#define CDIM 512
#define HDIM 128
#define WDIM 128
#define HWDIM (HDIM*WDIM)
#define SADMP 16
#define BHW 8
#define KKP 256

using short8 = __attribute__((ext_vector_type(8))) short;
using f32x4  = __attribute__((ext_vector_type(4))) float;

__device__ __forceinline__ unsigned short f2bf(float f) {
    unsigned u = __float_as_uint(f);
    unsigned r = (u + 0x7fffu + ((u >> 16) & 1u)) >> 16;
    return (unsigned short)r;
}
__device__ __forceinline__ float bf2f(unsigned short h) {
    return __uint_as_float(((unsigned)h) << 16);
}
__device__ __forceinline__ unsigned int ordf(float f) {
    unsigned u = __float_as_uint(f);
    return (u & 0x80000000u) ? ~u : (u | 0x80000000u);
}
// writer-side LDS drain + raw barrier. NO sched_barrier: next-step global
// loads may hoist/stay in flight across the barrier (no vmcnt drain).
__device__ __forceinline__ void step_barrier() {
    asm volatile("s_waitcnt lgkmcnt(0)" ::: "memory");
    __builtin_amdgcn_s_barrier();
}

// ---------------- K1a: channel-chunk partial sums (8 chunks of 64) ----------------
__global__ void resp_part_kernel(const float* __restrict__ A, float* __restrict__ part) {
    int gid = blockIdx.x * blockDim.x + threadIdx.x;   // (b*8+cq)*HW + hw
    int hw = gid & (HWDIM - 1);
    int rest = gid >> 14;
    int b = rest >> 3, cq = rest & 7;
    const float* p = A + (size_t)b * CDIM * HWDIM + (size_t)(cq * 64) * HWDIM + hw;
    float s0 = 0.f, s1 = 0.f, s2 = 0.f, s3 = 0.f;
    #pragma unroll 4
    for (int c = 0; c < 64; c += 4) {
        s0 += p[(size_t)(c + 0) * HWDIM];
        s1 += p[(size_t)(c + 1) * HWDIM];
        s2 += p[(size_t)(c + 2) * HWDIM];
        s3 += p[(size_t)(c + 3) * HWDIM];
    }
    part[gid] = (s0 + s1) + (s2 + s3);
}
// ---------------- K1b: combine (ascending cq -> deterministic) ----------------
__global__ void resp_comb_kernel(const float* __restrict__ part, float* __restrict__ resp) {
    int gid = blockIdx.x * blockDim.x + threadIdx.x;   // b*HW + hw
    int hw = gid & (HWDIM - 1);
    int b = gid >> 14;
    const float* p = part + (size_t)(b * 8) * HWDIM + hw;
    float s = 0.f;
    #pragma unroll
    for (int cq = 0; cq < 8; cq++) s += p[(size_t)cq * HWDIM];
    resp[gid] = s;
}

// ---------------- K2: per-window argmax (first occurrence) ----------------
__global__ void argmax_kernel(const float* __restrict__ resp, int* __restrict__ kp) {
    int win = blockIdx.x;                 // b*K + k
    int b = win / KKP, k = win % KKP;
    int bi = k / SADMP, bj = k % SADMP;
    int l = threadIdx.x;                  // 0..63 == loc
    int r = l >> 3, c = l & 7;
    int h = bi * BHW + r, w = bj * BHW + c;
    float v = resp[b * HWDIM + h * WDIM + w];
    int idx = l;
    #pragma unroll
    for (int off = 32; off; off >>= 1) {
        float ov = __shfl_down(v, off);
        int   oi = __shfl_down(idx, off);
        if (ov > v || (ov == v && oi < idx)) { v = ov; idx = oi; }
    }
    if (l == 0) {
        int row = bi * BHW + (idx >> 3);
        int col = bj * BHW + (idx & 7);
        kp[win] = row * WDIM + col;
    }
}

// ---------------- K3: gather + hi/lo convert into 16x16 MFMA A-frag order + dn ----
// frag (uint4): (b*2+term)*16384 + mf*1024 + q*64 + lane
//   lane holds A[m=mf*16+(lane&15)][c=q*32+(lane>>4)*8+j]
__global__ void convert_kernel(const float* __restrict__ A, const int* __restrict__ kp,
                               uint4* __restrict__ frag, float* __restrict__ dn) {
    int blk = blockIdx.x;                 // b*16 + mf
    int b = blk >> 4, mf = blk & 15;
    int t = threadIdx.x;                  // 0..255
    int l = t & 63, q0 = t >> 6;
    int ml = l & 15;
    int m  = mf * 16 + ml;
    int cg = (l >> 4) * 8;
    int idx = kp[b * KKP + m];
    const float* Ab = A + (size_t)b * CDIM * HWDIM + idx;
    float sq = 0.f;
    #pragma unroll
    for (int qq = 0; qq < 4; qq++) {
        int q = q0 * 4 + qq;
        unsigned hi[4], lo[4];
        #pragma unroll
        for (int jj = 0; jj < 4; jj++) {
            int c0 = q * 32 + cg + jj * 2;
            float v0 = Ab[(size_t)c0 * HWDIM];
            float v1 = Ab[(size_t)(c0 + 1) * HWDIM];
            sq = fmaf(v0, v0, sq);
            sq = fmaf(v1, v1, sq);
            unsigned short h0 = f2bf(v0), h1 = f2bf(v1);
            unsigned short g0 = f2bf(v0 - bf2f(h0)), g1 = f2bf(v1 - bf2f(h1));
            hi[jj] = (unsigned)h0 | ((unsigned)h1 << 16);
            lo[jj] = (unsigned)g0 | ((unsigned)g1 << 16);
        }
        frag[((size_t)b * 2 + 0) * 16384 + mf * 1024 + q * 64 + l] = make_uint4(hi[0], hi[1], hi[2], hi[3]);
        frag[((size_t)b * 2 + 1) * 16384 + mf * 1024 + q * 64 + l] = make_uint4(lo[0], lo[1], lo[2], lo[3]);
    }
    __shared__ float red[16][17];
    red[ml][(l >> 4) * 4 + q0] = sq;
    __syncthreads();
    if (t < 16) {
        float s = 0.f;
        #pragma unroll
        for (int i = 0; i < 16; i++) s += red[t][i];
        dn[b * KKP + mf * 16 + t] = s;
    }
}

// ---------------- K4: MFMA dist + argmin ----------------
// BM=256, BN=64, BK=64/step, 8 steps, 16x16x32, bf16 hi/lo 3-term.
// Double-buffered fragment-order LDS (0 conflicts), ONE raw s_barrier/step.
// A-frags REGISTER double-buffered: phase-B frags issued before phase-A
// MFMAs; next-step phase-A frags issued before phase-B MFMAs -> every
// global load has a full MFMA phase to land; raw barrier keeps them in
// flight across steps (no vmcnt drain anywhere in the loop).
__global__ __launch_bounds__(512) void dist_mfma_kernel(
    const uint4* __restrict__ fragA, const float* __restrict__ fb,
    const float* __restrict__ dn, unsigned long long* __restrict__ minkey)
{
    const int n0 = blockIdx.x * 64;
    const int b  = blockIdx.y;
    const int t  = threadIdx.x;
    const int l  = t & 63;
    const int w  = t >> 6;                // wave 0..7: rows w*32 .. w*32+31

    __shared__ char sb[2][16384];         // [buf][term:2][ch:2][nf:4][1024]
    __shared__ float bnp[8][64];
    __shared__ float bnf[64];
    __shared__ float dnl[256];

    if (t < 256) dnl[t] = dn[b * KKP + t];

    f32x4 acc[2][4] = {};                 // [mfl][nf]

    // staging map: thread (scol, sw) stages channels sw*8..+7 of col n0+scol
    const int scol = t & 63;
    const int sw   = t >> 6;
    const int wbase = ((sw >> 2) << 12) + ((scol >> 4) << 10) + (((((sw & 3) << 4) + (scol & 15))) << 4);
    const float* fbp = fb + (size_t)b * CDIM * HWDIM + (size_t)(sw * 8) * HWDIM + n0 + scol;
    float bnacc = 0.f;

    const short8* fA = (const short8*)fragA;
    const size_t a0Hi = ((size_t)b * 2 + 0) * 16384 + (size_t)(w * 2 + 0) * 1024 + l;
    const size_t a1Hi = ((size_t)b * 2 + 0) * 16384 + (size_t)(w * 2 + 1) * 1024 + l;
    const size_t a0Lo = ((size_t)b * 2 + 1) * 16384 + (size_t)(w * 2 + 0) * 1024 + l;
    const size_t a1Lo = ((size_t)b * 2 + 1) * 16384 + (size_t)(w * 2 + 1) * 1024 + l;

    float v[8];
    // prologue: load step0 fb, convert+write buf0, issue step1 fb loads,
    // prefetch step0 phase-A frags, barrier.
    #pragma unroll
    for (int i = 0; i < 8; i++) v[i] = fbp[(size_t)i * HWDIM];
    {
        unsigned hi[4], lo[4];
        #pragma unroll
        for (int jj = 0; jj < 4; jj++) {
            float v0 = v[jj * 2], v1 = v[jj * 2 + 1];
            bnacc = fmaf(v0, v0, bnacc);
            bnacc = fmaf(v1, v1, bnacc);
            unsigned short h0 = f2bf(v0), h1 = f2bf(v1);
            unsigned short g0 = f2bf(v0 - bf2f(h0)), g1 = f2bf(v1 - bf2f(h1));
            hi[jj] = (unsigned)h0 | ((unsigned)h1 << 16);
            lo[jj] = (unsigned)g0 | ((unsigned)g1 << 16);
        }
        *(uint4*)(&sb[0][wbase])        = make_uint4(hi[0], hi[1], hi[2], hi[3]);
        *(uint4*)(&sb[0][wbase + 8192]) = make_uint4(lo[0], lo[1], lo[2], lo[3]);
    }
    #pragma unroll
    for (int i = 0; i < 8; i++) v[i] = fbp[(size_t)(64 + i) * HWDIM];
    short8 aA0 = fA[a0Hi], aA1 = fA[a1Hi], aA2 = fA[a0Lo], aA3 = fA[a1Lo];
    step_barrier();

    for (int s = 0; s < 8; s++) {
        const int cur = s & 1;
        const char* rb = sb[cur];

        // issue phase-B a-frag loads (land during phase-A MFMAs)
        const size_t qB = (size_t)(s * 2 + 1) * 64;
        short8 aB0 = fA[a0Hi + qB];
        short8 aB1 = fA[a1Hi + qB];
        short8 aB2 = fA[a0Lo + qB];
        short8 aB3 = fA[a1Lo + qB];

        // ---- phase A: ch0 MFMAs (aA* prefetched last step / prologue)
        {
            const char* rp = rb + l * 16;
            #pragma unroll
            for (int nf = 0; nf < 4; nf++) {
                short8 bh = *(const short8*)(rp + nf * 1024);
                short8 bl = *(const short8*)(rp + nf * 1024 + 8192);
                acc[0][nf] = __builtin_amdgcn_mfma_f32_16x16x32_bf16(aA0, bh, acc[0][nf], 0, 0, 0);
                acc[0][nf] = __builtin_amdgcn_mfma_f32_16x16x32_bf16(aA0, bl, acc[0][nf], 0, 0, 0);
                acc[0][nf] = __builtin_amdgcn_mfma_f32_16x16x32_bf16(aA2, bh, acc[0][nf], 0, 0, 0);
                acc[1][nf] = __builtin_amdgcn_mfma_f32_16x16x32_bf16(aA1, bh, acc[1][nf], 0, 0, 0);
                acc[1][nf] = __builtin_amdgcn_mfma_f32_16x16x32_bf16(aA1, bl, acc[1][nf], 0, 0, 0);
                acc[1][nf] = __builtin_amdgcn_mfma_f32_16x16x32_bf16(aA3, bh, acc[1][nf], 0, 0, 0);
            }
        }

        // ---- staging: convert step s+1 -> buf^1; issue fb loads for s+2
        if (s < 7) {
            unsigned hi[4], lo[4];
            #pragma unroll
            for (int jj = 0; jj < 4; jj++) {
                float v0 = v[jj * 2], v1 = v[jj * 2 + 1];
                bnacc = fmaf(v0, v0, bnacc);
                bnacc = fmaf(v1, v1, bnacc);
                unsigned short h0 = f2bf(v0), h1 = f2bf(v1);
                unsigned short g0 = f2bf(v0 - bf2f(h0)), g1 = f2bf(v1 - bf2f(h1));
                hi[jj] = (unsigned)h0 | ((unsigned)h1 << 16);
                lo[jj] = (unsigned)g0 | ((unsigned)g1 << 16);
            }
            char* wp = (char*)sb[cur ^ 1] + wbase;
            *(uint4*)(wp)        = make_uint4(hi[0], hi[1], hi[2], hi[3]);
            *(uint4*)(wp + 8192) = make_uint4(lo[0], lo[1], lo[2], lo[3]);
            if (s < 6) {
                #pragma unroll
                for (int i = 0; i < 8; i++)
                    v[i] = fbp[(size_t)((s + 2) * 64 + i) * HWDIM];
            }
        }

        // issue next-step phase-A a-frag loads (stay in flight across barrier)
        if (s < 7) {
            const size_t qN = (size_t)(s * 2 + 2) * 64;
            aA0 = fA[a0Hi + qN];
            aA1 = fA[a1Hi + qN];
            aA2 = fA[a0Lo + qN];
            aA3 = fA[a1Lo + qN];
        }

        // ---- phase B: ch1 MFMAs (aB* issued at step start)
        {
            const char* rp = rb + 4096 + l * 16;
            #pragma unroll
            for (int nf = 0; nf < 4; nf++) {
                short8 bh = *(const short8*)(rp + nf * 1024);
                short8 bl = *(const short8*)(rp + nf * 1024 + 8192);
                acc[0][nf] = __builtin_amdgcn_mfma_f32_16x16x32_bf16(aB0, bh, acc[0][nf], 0, 0, 0);
                acc[0][nf] = __builtin_amdgcn_mfma_f32_16x16x32_bf16(aB0, bl, acc[0][nf], 0, 0, 0);
                acc[0][nf] = __builtin_amdgcn_mfma_f32_16x16x32_bf16(aB2, bh, acc[0][nf], 0, 0, 0);
                acc[1][nf] = __builtin_amdgcn_mfma_f32_16x16x32_bf16(aB1, bh, acc[1][nf], 0, 0, 0);
                acc[1][nf] = __builtin_amdgcn_mfma_f32_16x16x32_bf16(aB1, bl, acc[1][nf], 0, 0, 0);
                acc[1][nf] = __builtin_amdgcn_mfma_f32_16x16x32_bf16(aB3, bh, acc[1][nf], 0, 0, 0);
            }
        }

        if (s < 7) step_barrier();
    }

    // bn reduction
    bnp[sw][scol] = bnacc;
    __syncthreads();
    if (t < 64) {
        float s = 0.f;
        #pragma unroll
        for (int i = 0; i < 8; i++) s += bnp[i][t];
        bnf[t] = s;
    }
    __syncthreads();

    // epilogue: dist = dn - 2*cross + bn, packed argmin, atomicMin
    #pragma unroll
    for (int mfl = 0; mfl < 2; mfl++) {
        #pragma unroll
        for (int r = 0; r < 4; r++) {
            int m = w * 32 + mfl * 16 + (l >> 4) * 4 + r;
            float dnm = dnl[m];
            unsigned long long best = ~0ull;
            #pragma unroll
            for (int nf = 0; nf < 4; nf++) {
                int nloc = nf * 16 + (l & 15);
                float d = dnm - 2.f * acc[mfl][nf][r] + bnf[nloc];
                unsigned long long key = ((unsigned long long)ordf(d) << 32) | (unsigned)(n0 + nloc);
                if (key < best) best = key;
            }
            #pragma unroll
            for (int off = 1; off < 16; off <<= 1) {
                unsigned long long o = __shfl_xor(best, off);
                if (o < best) best = o;
            }
            if ((l & 15) == 0) atomicMin(&minkey[b * KKP + m], best);
        }
    }
}

// ---------------- K5: finalize ----------------
__global__ void finalize_kernel(const unsigned long long* __restrict__ minkey,
                                const int* __restrict__ kp,
                                float* __restrict__ out)
{
    int b = blockIdx.x;
    int k = threadIdx.x;
    unsigned long long key = minkey[b * KKP + k];
    unsigned n   = (unsigned)(key & 0xffffffffu);
    unsigned top = (unsigned)(key >> 32);
    unsigned fbits = (top & 0x80000000u) ? (top ^ 0x80000000u) : ~top;
    out[8 + b * KKP + k] = __uint_as_float(fbits);

    int idxA = kp[b * KKP + k];
    int rowA = idxA >> 7, colA = idxA & 127;
    int rowB = (int)(n >> 7), colB = (int)(n & 127);
    int drow = rowA - rowB, dcol = colA - colB;
    int code = (drow + 256) * 1024 + (dcol + 256);

    __shared__ int codes[KKP];
    __shared__ int keys[KKP];
    codes[k] = code;
    __syncthreads();
    int cnt = 0;
    for (int j = 0; j < KKP; j++) cnt += (codes[j] == code);
    keys[k] = cnt * 256 + (255 - k);
    __syncthreads();
    for (int s = 128; s; s >>= 1) {
        if (k < s) keys[k] = max(keys[k], keys[k + s]);
        __syncthreads();
    }
    if (k == 0) {
        int bestk = 255 - (keys[0] & 255);
        int bc = codes[bestk];
        int dr = bc / 1024 - 256, dc = bc % 1024 - 256;
        out[b * 2 + 0] = (float)dr;
        out[b * 2 + 1] = (float)dc;
    }
}

extern "C" void kernel_launch(void* const* d_in, const int* in_sizes, int n_in,
                              void* d_out, int out_size, void* d_ws, size_t ws_size,
                              hipStream_t stream) {
    const float* A  = (const float*)d_in[0];
    const float* Bf = (const float*)d_in[1];
    float* out = (float*)d_out;
    char* ws = (char*)d_ws;

    float* resp = (float*)ws;                                   // 256 KB
    int*   kp   = (int*)(ws + 262144);                          // 4 KB
    float* dn   = (float*)(ws + 266240);                        // 4 KB
    unsigned long long* minkey = (unsigned long long*)(ws + 270336); // 8 KB
    uint4* frag = (uint4*)(ws + 278528);                        // 2 MB
    float* part = (float*)(ws + 278528 + 2097152);              // 2 MB

    hipMemsetAsync(minkey, 0xFF, BDIM * KKP * sizeof(unsigned long long), stream);
    resp_part_kernel<<<BDIM * 8 * HWDIM / 256, 256, 0, stream>>>(A, part);
    resp_comb_kernel<<<BDIM * HWDIM / 256, 256, 0, stream>>>(part, resp);
    argmax_kernel<<<BDIM * KKP, 64, 0, stream>>>(resp, kp);
    convert_kernel<<<BDIM * 16, 256, 0, stream>>>(A, kp, frag, dn);
    dist_mfma_kernel<<<dim3(256, BDIM), 512, 0, stream>>>(frag, Bf, dn, minkey);
    finalize_kernel<<<BDIM, KKP, 0, stream>>>(minkey, kp, out);
}

// Round 10
// 117.568 us; speedup vs baseline: 1.6238x; 1.1567x over previous
//
#include <hip/hip_runtime.h>
#include <stdint.h>

#define BDIM 4
#define CDIM 512
#define HDIM 128
#define WDIM 128
#define HWDIM (HDIM*WDIM)
#define SADMP 16
#define BHW 8
#define KKP 256

using short8 = __attribute__((ext_vector_type(8))) short;
using f32x4  = __attribute__((ext_vector_type(4))) float;

__device__ __forceinline__ unsigned short f2bf(float f) {
    unsigned u = __float_as_uint(f);
    unsigned r = (u + 0x7fffu + ((u >> 16) & 1u)) >> 16;
    return (unsigned short)r;
}
__device__ __forceinline__ float bf2f(unsigned short h) {
    return __uint_as_float(((unsigned)h) << 16);
}
__device__ __forceinline__ unsigned int ordf(float f) {
    unsigned u = __float_as_uint(f);
    return (u & 0x80000000u) ? ~u : (u | 0x80000000u);
}
// writer-side LDS drain + raw barrier. NO vmcnt drain: global loads stay in
// flight across steps.
__device__ __forceinline__ void step_barrier() {
    asm volatile("s_waitcnt lgkmcnt(0)" ::: "memory");
    __builtin_amdgcn_s_barrier();
}

// ---------------- K1a: channel-chunk partial sums (8 chunks of 64) ----------------
__global__ void resp_part_kernel(const float* __restrict__ A, float* __restrict__ part) {
    int gid = blockIdx.x * blockDim.x + threadIdx.x;   // (b*8+cq)*HW + hw
    int hw = gid & (HWDIM - 1);
    int rest = gid >> 14;
    int b = rest >> 3, cq = rest & 7;
    const float* p = A + (size_t)b * CDIM * HWDIM + (size_t)(cq * 64) * HWDIM + hw;
    float s0 = 0.f, s1 = 0.f, s2 = 0.f, s3 = 0.f;
    #pragma unroll 4
    for (int c = 0; c < 64; c += 4) {
        s0 += p[(size_t)(c + 0) * HWDIM];
        s1 += p[(size_t)(c + 1) * HWDIM];
        s2 += p[(size_t)(c + 2) * HWDIM];
        s3 += p[(size_t)(c + 3) * HWDIM];
    }
    part[gid] = (s0 + s1) + (s2 + s3);
}
// ---------------- K1b: combine (ascending cq -> deterministic) ----------------
__global__ void resp_comb_kernel(const float* __restrict__ part, float* __restrict__ resp) {
    int gid = blockIdx.x * blockDim.x + threadIdx.x;   // b*HW + hw
    int hw = gid & (HWDIM - 1);
    int b = gid >> 14;
    const float* p = part + (size_t)(b * 8) * HWDIM + hw;
    float s = 0.f;
    #pragma unroll
    for (int cq = 0; cq < 8; cq++) s += p[(size_t)cq * HWDIM];
    resp[gid] = s;
}

// ---------------- K2: per-window argmax (first occurrence) ----------------
__global__ void argmax_kernel(const float* __restrict__ resp, int* __restrict__ kp) {
    int win = blockIdx.x;                 // b*K + k
    int b = win / KKP, k = win % KKP;
    int bi = k / SADMP, bj = k % SADMP;
    int l = threadIdx.x;                  // 0..63 == loc
    int r = l >> 3, c = l & 7;
    int h = bi * BHW + r, w = bj * BHW + c;
    float v = resp[b * HWDIM + h * WDIM + w];
    int idx = l;
    #pragma unroll
    for (int off = 32; off; off >>= 1) {
        float ov = __shfl_down(v, off);
        int   oi = __shfl_down(idx, off);
        if (ov > v || (ov == v && oi < idx)) { v = ov; idx = oi; }
    }
    if (l == 0) {
        int row = bi * BHW + (idx >> 3);
        int col = bj * BHW + (idx & 7);
        kp[win] = row * WDIM + col;
    }
}

// ---------------- K3: gather + hi/lo convert into 16x16 MFMA A-frag order + dn ----
__global__ void convert_kernel(const float* __restrict__ A, const int* __restrict__ kp,
                               uint4* __restrict__ frag, float* __restrict__ dn) {
    int blk = blockIdx.x;                 // b*16 + mf
    int b = blk >> 4, mf = blk & 15;
    int t = threadIdx.x;                  // 0..255
    int l = t & 63, q0 = t >> 6;
    int ml = l & 15;
    int m  = mf * 16 + ml;
    int cg = (l >> 4) * 8;
    int idx = kp[b * KKP + m];
    const float* Ab = A + (size_t)b * CDIM * HWDIM + idx;
    float sq = 0.f;
    #pragma unroll
    for (int qq = 0; qq < 4; qq++) {
        int q = q0 * 4 + qq;
        unsigned hi[4], lo[4];
        #pragma unroll
        for (int jj = 0; jj < 4; jj++) {
            int c0 = q * 32 + cg + jj * 2;
            float v0 = Ab[(size_t)c0 * HWDIM];
            float v1 = Ab[(size_t)(c0 + 1) * HWDIM];
            sq = fmaf(v0, v0, sq);
            sq = fmaf(v1, v1, sq);
            unsigned short h0 = f2bf(v0), h1 = f2bf(v1);
            unsigned short g0 = f2bf(v0 - bf2f(h0)), g1 = f2bf(v1 - bf2f(h1));
            hi[jj] = (unsigned)h0 | ((unsigned)h1 << 16);
            lo[jj] = (unsigned)g0 | ((unsigned)g1 << 16);
        }
        frag[((size_t)b * 2 + 0) * 16384 + mf * 1024 + q * 64 + l] = make_uint4(hi[0], hi[1], hi[2], hi[3]);
        frag[((size_t)b * 2 + 1) * 16384 + mf * 1024 + q * 64 + l] = make_uint4(lo[0], lo[1], lo[2], lo[3]);
    }
    __shared__ float red[16][17];
    red[ml][(l >> 4) * 4 + q0] = sq;
    __syncthreads();
    if (t < 16) {
        float s = 0.f;
        #pragma unroll
        for (int i = 0; i < 16; i++) s += red[t][i];
        dn[b * KKP + mf * 16 + t] = s;
    }
}

// ---------------- K4: MFMA dist + argmin ----------------
// BM=256, BN=64, BK=64/step, 8 steps, 16x16x32, bf16 hi/lo 3-term.
// Fragment-order dbuf LDS (0 conflicts), ONE raw s_barrier/step.
// A-frags register-double-buffered CORRECTLY: next-step ch0 frags load into
// temps aN*, cluster consumes aA*, commit aA=aN after the cluster (loads
// still in flight across the barrier). Merged 48-MFMA cluster in setprio
// (T5); bijective batch-major XCD swizzle (T1).
__global__ __launch_bounds__(512) void dist_mfma_kernel(
    const uint4* __restrict__ fragA, const float* __restrict__ fb,
    const float* __restrict__ dn, unsigned long long* __restrict__ minkey)
{
    // T1: bijective XCD swizzle, batch-major (1024 blocks, 1024%8==0).
    const int u    = blockIdx.x;
    const int g    = (u & 7) * 128 + (u >> 3);
    const int b    = g >> 8;
    const int n0   = (g & 255) * 64;

    const int t  = threadIdx.x;
    const int l  = t & 63;
    const int w  = t >> 6;                // wave 0..7: rows w*32 .. w*32+31

    __shared__ char sb[2][16384];         // [buf][term:2][ch:2][nf:4][1024]
    __shared__ float bnp[8][64];
    __shared__ float bnf[64];
    __shared__ float dnl[256];

    if (t < 256) dnl[t] = dn[b * KKP + t];

    f32x4 acc[2][4] = {};                 // [mfl][nf]

    const int scol = t & 63;
    const int sw   = t >> 6;
    const int wbase = ((sw >> 2) << 12) + ((scol >> 4) << 10) + (((((sw & 3) << 4) + (scol & 15))) << 4);
    const float* fbp = fb + (size_t)b * CDIM * HWDIM + (size_t)(sw * 8) * HWDIM + n0 + scol;
    float bnacc = 0.f;

    const short8* fA = (const short8*)fragA;
    const size_t a0Hi = ((size_t)b * 2 + 0) * 16384 + (size_t)(w * 2 + 0) * 1024 + l;
    const size_t a1Hi = ((size_t)b * 2 + 0) * 16384 + (size_t)(w * 2 + 1) * 1024 + l;
    const size_t a0Lo = ((size_t)b * 2 + 1) * 16384 + (size_t)(w * 2 + 0) * 1024 + l;
    const size_t a1Lo = ((size_t)b * 2 + 1) * 16384 + (size_t)(w * 2 + 1) * 1024 + l;

    float v[8];
    // prologue: step0 fb -> buf0; step1 fb loads; step0 ch0 frags; barrier.
    #pragma unroll
    for (int i = 0; i < 8; i++) v[i] = fbp[(size_t)i * HWDIM];
    {
        unsigned hi[4], lo[4];
        #pragma unroll
        for (int jj = 0; jj < 4; jj++) {
            float v0 = v[jj * 2], v1 = v[jj * 2 + 1];
            bnacc = fmaf(v0, v0, bnacc);
            bnacc = fmaf(v1, v1, bnacc);
            unsigned short h0 = f2bf(v0), h1 = f2bf(v1);
            unsigned short g0 = f2bf(v0 - bf2f(h0)), g1 = f2bf(v1 - bf2f(h1));
            hi[jj] = (unsigned)h0 | ((unsigned)h1 << 16);
            lo[jj] = (unsigned)g0 | ((unsigned)g1 << 16);
        }
        *(uint4*)(&sb[0][wbase])        = make_uint4(hi[0], hi[1], hi[2], hi[3]);
        *(uint4*)(&sb[0][wbase + 8192]) = make_uint4(lo[0], lo[1], lo[2], lo[3]);
    }
    #pragma unroll
    for (int i = 0; i < 8; i++) v[i] = fbp[(size_t)(64 + i) * HWDIM];
    short8 aA0 = fA[a0Hi], aA1 = fA[a1Hi], aA2 = fA[a0Lo], aA3 = fA[a1Lo];
    step_barrier();

    for (int s = 0; s < 8; s++) {
        const int cur = s & 1;
        const char* rb = sb[cur];

        // staging: convert step s+1 -> buf^1; issue fb loads for s+2.
        if (s < 7) {
            unsigned hi[4], lo[4];
            #pragma unroll
            for (int jj = 0; jj < 4; jj++) {
                float v0 = v[jj * 2], v1 = v[jj * 2 + 1];
                bnacc = fmaf(v0, v0, bnacc);
                bnacc = fmaf(v1, v1, bnacc);
                unsigned short h0 = f2bf(v0), h1 = f2bf(v1);
                unsigned short g0 = f2bf(v0 - bf2f(h0)), g1 = f2bf(v1 - bf2f(h1));
                hi[jj] = (unsigned)h0 | ((unsigned)h1 << 16);
                lo[jj] = (unsigned)g0 | ((unsigned)g1 << 16);
            }
            char* wp = (char*)sb[cur ^ 1] + wbase;
            *(uint4*)(wp)        = make_uint4(hi[0], hi[1], hi[2], hi[3]);
            *(uint4*)(wp + 8192) = make_uint4(lo[0], lo[1], lo[2], lo[3]);
            if (s < 6) {
                #pragma unroll
                for (int i = 0; i < 8; i++)
                    v[i] = fbp[(size_t)((s + 2) * 64 + i) * HWDIM];
            }
        }

        // issue ch1 A-frag loads (land under the first 24 MFMAs)
        const size_t qB = (size_t)(s * 2 + 1) * 64;
        short8 aB0 = fA[a0Hi + qB];
        short8 aB1 = fA[a1Hi + qB];
        short8 aB2 = fA[a0Lo + qB];
        short8 aB3 = fA[a1Lo + qB];

        // issue NEXT-step ch0 A-frag loads into TEMPS (aA* still live below)
        short8 aN0 = aA0, aN1 = aA1, aN2 = aA2, aN3 = aA3;
        if (s < 7) {
            const size_t qN = (size_t)(s * 2 + 2) * 64;
            aN0 = fA[a0Hi + qN];
            aN1 = fA[a1Hi + qN];
            aN2 = fA[a0Lo + qN];
            aN3 = fA[a1Lo + qN];
        }

        // merged 48-MFMA cluster under raised priority (T5)
        {
            const char* rp0 = rb + l * 16;
            const char* rp1 = rb + 4096 + l * 16;
            __builtin_amdgcn_s_setprio(1);
            #pragma unroll
            for (int nf = 0; nf < 4; nf++) {
                short8 bh = *(const short8*)(rp0 + nf * 1024);
                short8 bl = *(const short8*)(rp0 + nf * 1024 + 8192);
                acc[0][nf] = __builtin_amdgcn_mfma_f32_16x16x32_bf16(aA0, bh, acc[0][nf], 0, 0, 0);
                acc[0][nf] = __builtin_amdgcn_mfma_f32_16x16x32_bf16(aA0, bl, acc[0][nf], 0, 0, 0);
                acc[0][nf] = __builtin_amdgcn_mfma_f32_16x16x32_bf16(aA2, bh, acc[0][nf], 0, 0, 0);
                acc[1][nf] = __builtin_amdgcn_mfma_f32_16x16x32_bf16(aA1, bh, acc[1][nf], 0, 0, 0);
                acc[1][nf] = __builtin_amdgcn_mfma_f32_16x16x32_bf16(aA1, bl, acc[1][nf], 0, 0, 0);
                acc[1][nf] = __builtin_amdgcn_mfma_f32_16x16x32_bf16(aA3, bh, acc[1][nf], 0, 0, 0);
            }
            #pragma unroll
            for (int nf = 0; nf < 4; nf++) {
                short8 bh = *(const short8*)(rp1 + nf * 1024);
                short8 bl = *(const short8*)(rp1 + nf * 1024 + 8192);
                acc[0][nf] = __builtin_amdgcn_mfma_f32_16x16x32_bf16(aB0, bh, acc[0][nf], 0, 0, 0);
                acc[0][nf] = __builtin_amdgcn_mfma_f32_16x16x32_bf16(aB0, bl, acc[0][nf], 0, 0, 0);
                acc[0][nf] = __builtin_amdgcn_mfma_f32_16x16x32_bf16(aB2, bh, acc[0][nf], 0, 0, 0);
                acc[1][nf] = __builtin_amdgcn_mfma_f32_16x16x32_bf16(aB1, bh, acc[1][nf], 0, 0, 0);
                acc[1][nf] = __builtin_amdgcn_mfma_f32_16x16x32_bf16(aB1, bl, acc[1][nf], 0, 0, 0);
                acc[1][nf] = __builtin_amdgcn_mfma_f32_16x16x32_bf16(aB3, bh, acc[1][nf], 0, 0, 0);
            }
            __builtin_amdgcn_s_setprio(0);
        }

        // commit A reg-dbuf for next step (loads stay in flight across barrier)
        aA0 = aN0; aA1 = aN1; aA2 = aN2; aA3 = aN3;
        if (s < 7) step_barrier();
    }

    // bn reduction
    bnp[sw][scol] = bnacc;
    __syncthreads();
    if (t < 64) {
        float s = 0.f;
        #pragma unroll
        for (int i = 0; i < 8; i++) s += bnp[i][t];
        bnf[t] = s;
    }
    __syncthreads();

    // epilogue: dist = dn - 2*cross + bn, packed argmin, atomicMin
    #pragma unroll
    for (int mfl = 0; mfl < 2; mfl++) {
        #pragma unroll
        for (int r = 0; r < 4; r++) {
            int m = w * 32 + mfl * 16 + (l >> 4) * 4 + r;
            float dnm = dnl[m];
            unsigned long long best = ~0ull;
            #pragma unroll
            for (int nf = 0; nf < 4; nf++) {
                int nloc = nf * 16 + (l & 15);
                float d = dnm - 2.f * acc[mfl][nf][r] + bnf[nloc];
                unsigned long long key = ((unsigned long long)ordf(d) << 32) | (unsigned)(n0 + nloc);
                if (key < best) best = key;
            }
            #pragma unroll
            for (int off = 1; off < 16; off <<= 1) {
                unsigned long long o = __shfl_xor(best, off);
                if (o < best) best = o;
            }
            if ((l & 15) == 0) atomicMin(&minkey[b * KKP + m], best);
        }
    }
}

// ---------------- K5: finalize ----------------
__global__ void finalize_kernel(const unsigned long long* __restrict__ minkey,
                                const int* __restrict__ kp,
                                float* __restrict__ out)
{
    int b = blockIdx.x;
    int k = threadIdx.x;
    unsigned long long key = minkey[b * KKP + k];
    unsigned n   = (unsigned)(key & 0xffffffffu);
    unsigned top = (unsigned)(key >> 32);
    unsigned fbits = (top & 0x80000000u) ? (top ^ 0x80000000u) : ~top;
    out[8 + b * KKP + k] = __uint_as_float(fbits);

    int idxA = kp[b * KKP + k];
    int rowA = idxA >> 7, colA = idxA & 127;
    int rowB = (int)(n >> 7), colB = (int)(n & 127);
    int drow = rowA - rowB, dcol = colA - colB;
    int code = (drow + 256) * 1024 + (dcol + 256);

    __shared__ int codes[KKP];
    __shared__ int keys[KKP];
    codes[k] = code;
    __syncthreads();
    int cnt = 0;
    for (int j = 0; j < KKP; j++) cnt += (codes[j] == code);
    keys[k] = cnt * 256 + (255 - k);
    __syncthreads();
    for (int s = 128; s; s >>= 1) {
        if (k < s) keys[k] = max(keys[k], keys[k + s]);
        __syncthreads();
    }
    if (k == 0) {
        int bestk = 255 - (keys[0] & 255);
        int bc = codes[bestk];
        int dr = bc / 1024 - 256, dc = bc % 1024 - 256;
        out[b * 2 + 0] = (float)dr;
        out[b * 2 + 1] = (float)dc;
    }
}

extern "C" void kernel_launch(void* const* d_in, const int* in_sizes, int n_in,
                              void* d_out, int out_size, void* d_ws, size_t ws_size,
                              hipStream_t stream) {
    const float* A  = (const float*)d_in[0];
    const float* Bf = (const float*)d_in[1];
    float* out = (float*)d_out;
    char* ws = (char*)d_ws;

    float* resp = (float*)ws;                                   // 256 KB
    int*   kp   = (int*)(ws + 262144);                          // 4 KB
    float* dn   = (float*)(ws + 266240);                        // 4 KB
    unsigned long long* minkey = (unsigned long long*)(ws + 270336); // 8 KB
    uint4* frag = (uint4*)(ws + 278528);                        // 2 MB
    float* part = (float*)(ws + 278528 + 2097152);              // 2 MB

    hipMemsetAsync(minkey, 0xFF, BDIM * KKP * sizeof(unsigned long long), stream);
    resp_part_kernel<<<BDIM * 8 * HWDIM / 256, 256, 0, stream>>>(A, part);
    resp_comb_kernel<<<BDIM * HWDIM / 256, 256, 0, stream>>>(part, resp);
    argmax_kernel<<<BDIM * KKP, 64, 0, stream>>>(resp, kp);
    convert_kernel<<<BDIM * 16, 256, 0, stream>>>(A, kp, frag, dn);
    dist_mfma_kernel<<<1024, 512, 0, stream>>>(frag, Bf, dn, minkey);
    finalize_kernel<<<BDIM, KKP, 0, stream>>>(minkey, kp, out);
}

// Round 11
// 117.212 us; speedup vs baseline: 1.6287x; 1.0030x over previous
//
#include <hip/hip_runtime.h>
#include <stdint.h>

#define BDIM 4
#define CDIM 512
#define HDIM 128
#define WDIM 128
#define HWDIM (HDIM*WDIM)
#define SADMP 16
#define BHW 8
#define KKP 256

using short8 = __attribute__((ext_vector_type(8))) short;
using f32x4  = __attribute__((ext_vector_type(4))) float;

__device__ __forceinline__ unsigned short f2bf(float f) {
    unsigned u = __float_as_uint(f);
    unsigned r = (u + 0x7fffu + ((u >> 16) & 1u)) >> 16;
    return (unsigned short)r;
}
__device__ __forceinline__ float bf2f(unsigned short h) {
    return __uint_as_float(((unsigned)h) << 16);
}
__device__ __forceinline__ unsigned int ordf(float f) {
    unsigned u = __float_as_uint(f);
    return (u & 0x80000000u) ? ~u : (u | 0x80000000u);
}
// writer-side LDS drain + raw barrier; no vmcnt drain (globals stay in flight)
__device__ __forceinline__ void step_barrier() {
    asm volatile("s_waitcnt lgkmcnt(0)" ::: "memory");
    __builtin_amdgcn_s_barrier();
}

// ---------------- K1a: channel-chunk partial sums (8 chunks of 64) ----------------
__global__ void resp_part_kernel(const float* __restrict__ A, float* __restrict__ part) {
    int gid = blockIdx.x * blockDim.x + threadIdx.x;
    int hw = gid & (HWDIM - 1);
    int rest = gid >> 14;
    int b = rest >> 3, cq = rest & 7;
    const float* p = A + (size_t)b * CDIM * HWDIM + (size_t)(cq * 64) * HWDIM + hw;
    float s0 = 0.f, s1 = 0.f, s2 = 0.f, s3 = 0.f;
    #pragma unroll 4
    for (int c = 0; c < 64; c += 4) {
        s0 += p[(size_t)(c + 0) * HWDIM];
        s1 += p[(size_t)(c + 1) * HWDIM];
        s2 += p[(size_t)(c + 2) * HWDIM];
        s3 += p[(size_t)(c + 3) * HWDIM];
    }
    part[gid] = (s0 + s1) + (s2 + s3);
}
// ---------------- K1b: combine (ascending cq -> deterministic) ----------------
__global__ void resp_comb_kernel(const float* __restrict__ part, float* __restrict__ resp) {
    int gid = blockIdx.x * blockDim.x + threadIdx.x;
    int hw = gid & (HWDIM - 1);
    int b = gid >> 14;
    const float* p = part + (size_t)(b * 8) * HWDIM + hw;
    float s = 0.f;
    #pragma unroll
    for (int cq = 0; cq < 8; cq++) s += p[(size_t)cq * HWDIM];
    resp[gid] = s;
}

// ---------------- K2: per-window argmax (first occurrence) ----------------
__global__ void argmax_kernel(const float* __restrict__ resp, int* __restrict__ kp) {
    int win = blockIdx.x;
    int b = win / KKP, k = win % KKP;
    int bi = k / SADMP, bj = k % SADMP;
    int l = threadIdx.x;
    int r = l >> 3, c = l & 7;
    int h = bi * BHW + r, w = bj * BHW + c;
    float v = resp[b * HWDIM + h * WDIM + w];
    int idx = l;
    #pragma unroll
    for (int off = 32; off; off >>= 1) {
        float ov = __shfl_down(v, off);
        int   oi = __shfl_down(idx, off);
        if (ov > v || (ov == v && oi < idx)) { v = ov; idx = oi; }
    }
    if (l == 0) {
        int row = bi * BHW + (idx >> 3);
        int col = bj * BHW + (idx & 7);
        kp[win] = row * WDIM + col;
    }
}

// ---------------- K3: gather + hi/lo convert into 16x16 MFMA A-frag order + dn ----
__global__ void convert_kernel(const float* __restrict__ A, const int* __restrict__ kp,
                               uint4* __restrict__ frag, float* __restrict__ dn) {
    int blk = blockIdx.x;                 // b*16 + mf
    int b = blk >> 4, mf = blk & 15;
    int t = threadIdx.x;
    int l = t & 63, q0 = t >> 6;
    int ml = l & 15;
    int m  = mf * 16 + ml;
    int cg = (l >> 4) * 8;
    int idx = kp[b * KKP + m];
    const float* Ab = A + (size_t)b * CDIM * HWDIM + idx;
    float sq = 0.f;
    #pragma unroll
    for (int qq = 0; qq < 4; qq++) {
        int q = q0 * 4 + qq;
        unsigned hi[4], lo[4];
        #pragma unroll
        for (int jj = 0; jj < 4; jj++) {
            int c0 = q * 32 + cg + jj * 2;
            float v0 = Ab[(size_t)c0 * HWDIM];
            float v1 = Ab[(size_t)(c0 + 1) * HWDIM];
            sq = fmaf(v0, v0, sq);
            sq = fmaf(v1, v1, sq);
            unsigned short h0 = f2bf(v0), h1 = f2bf(v1);
            unsigned short g0 = f2bf(v0 - bf2f(h0)), g1 = f2bf(v1 - bf2f(h1));
            hi[jj] = (unsigned)h0 | ((unsigned)h1 << 16);
            lo[jj] = (unsigned)g0 | ((unsigned)g1 << 16);
        }
        frag[((size_t)b * 2 + 0) * 16384 + mf * 1024 + q * 64 + l] = make_uint4(hi[0], hi[1], hi[2], hi[3]);
        frag[((size_t)b * 2 + 1) * 16384 + mf * 1024 + q * 64 + l] = make_uint4(lo[0], lo[1], lo[2], lo[3]);
    }
    __shared__ float red[16][17];
    red[ml][(l >> 4) * 4 + q0] = sq;
    __syncthreads();
    if (t < 16) {
        float s = 0.f;
        #pragma unroll
        for (int i = 0; i < 16; i++) s += red[t][i];
        dn[b * KKP + mf * 16 + t] = s;
    }
}

// ---------------- K4: MFMA dist + argmin ----------------
// BM=256, BN=64, BK=128/step, 4 steps, 16x16x32, bf16 hi/lo 3-term.
// Per-step LDS buffer 32 KB = [term:2][q:4][nf:4][1KB] fragment-order
// (16B-contiguous writes+reads, 0 conflicts), double-buffered (64 KB).
// 4 barriers/block (halved); 96-MFMA setprio cluster per step with one-q
// lookahead A-frag rotation; fb v[16] prefetched 2 steps ahead (in flight
// across barriers). T1 bijective batch-major XCD swizzle.
__global__ __launch_bounds__(512) void dist_mfma_kernel(
    const uint4* __restrict__ fragA, const float* __restrict__ fb,
    const float* __restrict__ dn, unsigned long long* __restrict__ minkey)
{
    const int u    = blockIdx.x;          // 1024 blocks, 1024%8==0
    const int g    = (u & 7) * 128 + (u >> 3);
    const int b    = g >> 8;
    const int n0   = (g & 255) * 64;

    const int t  = threadIdx.x;
    const int l  = t & 63;
    const int w  = t >> 6;                // wave 0..7: rows w*32 .. w*32+31

    __shared__ char sb[2][32768];         // [buf][term:2][q:4][nf:4][1024]
    __shared__ float bnp[8][64];
    __shared__ float bnf[64];
    __shared__ float dnl[256];

    if (t < 256) dnl[t] = dn[b * KKP + t];

    f32x4 acc[2][4] = {};                 // [mfl][nf]

    // staging map: thread (scol, sw) stages channels sw*16..+15 per step,
    // as 2 chunks of 8 (cj = sw*2 + j): LDS offset
    //   (cj>>2)*4096 + (scol>>4)*1024 + ((cj&3)*16 + (scol&15))*16, term +16384
    const int scol = t & 63;
    const int sw   = t >> 6;
    const int cj0  = sw * 2;
    const int wb0  = ((cj0 >> 2) << 12) + ((scol >> 4) << 10) + ((((cj0 & 3) << 4) + (scol & 15)) << 4);
    const int cj1  = sw * 2 + 1;
    const int wb1  = ((cj1 >> 2) << 12) + ((scol >> 4) << 10) + ((((cj1 & 3) << 4) + (scol & 15)) << 4);
    const float* fbp = fb + (size_t)b * CDIM * HWDIM + (size_t)(sw * 16) * HWDIM + n0 + scol;
    float bnacc = 0.f;

    const short8* fA = (const short8*)fragA;
    const size_t a0Hi = ((size_t)b * 2 + 0) * 16384 + (size_t)(w * 2 + 0) * 1024 + l;
    const size_t a1Hi = ((size_t)b * 2 + 0) * 16384 + (size_t)(w * 2 + 1) * 1024 + l;
    const size_t a0Lo = ((size_t)b * 2 + 1) * 16384 + (size_t)(w * 2 + 0) * 1024 + l;
    const size_t a1Lo = ((size_t)b * 2 + 1) * 16384 + (size_t)(w * 2 + 1) * 1024 + l;

    float v[16];

    // ---- staging helper expanded inline (chunk j of 8 values -> frag LDS)
#define STAGE_CHUNK(BUFP, J, WB)                                               \
    {                                                                          \
        unsigned hi[4], lo[4];                                                 \
        _Pragma("unroll")                                                      \
        for (int p = 0; p < 4; p++) {                                          \
            float v0 = v[(J) * 8 + 2 * p], v1 = v[(J) * 8 + 2 * p + 1];        \
            bnacc = fmaf(v0, v0, bnacc);                                       \
            bnacc = fmaf(v1, v1, bnacc);                                       \
            unsigned short h0 = f2bf(v0), h1 = f2bf(v1);                       \
            unsigned short g0 = f2bf(v0 - bf2f(h0)), g1 = f2bf(v1 - bf2f(h1)); \
            hi[p] = (unsigned)h0 | ((unsigned)h1 << 16);                       \
            lo[p] = (unsigned)g0 | ((unsigned)g1 << 16);                       \
        }                                                                      \
        *(uint4*)((BUFP) + (WB))         = make_uint4(hi[0], hi[1], hi[2], hi[3]); \
        *(uint4*)((BUFP) + (WB) + 16384) = make_uint4(lo[0], lo[1], lo[2], lo[3]); \
    }

    // prologue: step0 fb -> buf0; step1 fb loads; q=0 A-frags; barrier.
    #pragma unroll
    for (int i = 0; i < 16; i++) v[i] = fbp[(size_t)i * HWDIM];
    STAGE_CHUNK((char*)sb[0], 0, wb0)
    STAGE_CHUNK((char*)sb[0], 1, wb1)
    #pragma unroll
    for (int i = 0; i < 16; i++) v[i] = fbp[(size_t)(128 + i) * HWDIM];
    short8 fh0 = fA[a0Hi], fh1 = fA[a1Hi], fl0 = fA[a0Lo], fl1 = fA[a1Lo];
    step_barrier();

    for (int s = 0; s < 4; s++) {
        const int cur = s & 1;
        const char* rb = sb[cur];

        // staging: convert step s+1 -> buf^1; issue fb loads for s+2.
        if (s < 3) {
            char* wbuf = (char*)sb[cur ^ 1];
            STAGE_CHUNK(wbuf, 0, wb0)
            STAGE_CHUNK(wbuf, 1, wb1)
            if (s < 2) {
                #pragma unroll
                for (int i = 0; i < 16; i++)
                    v[i] = fbp[(size_t)((s + 2) * 128 + i) * HWDIM];
            }
        }

        // 96-MFMA cluster with one-q-lookahead A-frag rotation (T5)
        __builtin_amdgcn_s_setprio(1);
        #pragma unroll
        for (int p = 0; p < 4; p++) {
            const int qg = s * 4 + p;     // global q 0..15
            short8 nh0 = fh0, nh1 = fh1, nl0 = fl0, nl1 = fl1;
            if (qg < 15) {
                const size_t qn = (size_t)(qg + 1) * 64;
                nh0 = fA[a0Hi + qn];
                nh1 = fA[a1Hi + qn];
                nl0 = fA[a0Lo + qn];
                nl1 = fA[a1Lo + qn];
            }
            const char* rp = rb + p * 4096 + l * 16;
            #pragma unroll
            for (int nf = 0; nf < 4; nf++) {
                short8 bh = *(const short8*)(rp + nf * 1024);
                short8 bl = *(const short8*)(rp + nf * 1024 + 16384);
                acc[0][nf] = __builtin_amdgcn_mfma_f32_16x16x32_bf16(fh0, bh, acc[0][nf], 0, 0, 0);
                acc[0][nf] = __builtin_amdgcn_mfma_f32_16x16x32_bf16(fh0, bl, acc[0][nf], 0, 0, 0);
                acc[0][nf] = __builtin_amdgcn_mfma_f32_16x16x32_bf16(fl0, bh, acc[0][nf], 0, 0, 0);
                acc[1][nf] = __builtin_amdgcn_mfma_f32_16x16x32_bf16(fh1, bh, acc[1][nf], 0, 0, 0);
                acc[1][nf] = __builtin_amdgcn_mfma_f32_16x16x32_bf16(fh1, bl, acc[1][nf], 0, 0, 0);
                acc[1][nf] = __builtin_amdgcn_mfma_f32_16x16x32_bf16(fl1, bh, acc[1][nf], 0, 0, 0);
            }
            fh0 = nh0; fh1 = nh1; fl0 = nl0; fl1 = nl1;
        }
        __builtin_amdgcn_s_setprio(0);

        if (s < 3) step_barrier();
    }
#undef STAGE_CHUNK

    // bn reduction
    bnp[sw][scol] = bnacc;
    __syncthreads();
    if (t < 64) {
        float s = 0.f;
        #pragma unroll
        for (int i = 0; i < 8; i++) s += bnp[i][t];
        bnf[t] = s;
    }
    __syncthreads();

    // epilogue: dist = dn - 2*cross + bn, packed argmin, atomicMin
    #pragma unroll
    for (int mfl = 0; mfl < 2; mfl++) {
        #pragma unroll
        for (int r = 0; r < 4; r++) {
            int m = w * 32 + mfl * 16 + (l >> 4) * 4 + r;
            float dnm = dnl[m];
            unsigned long long best = ~0ull;
            #pragma unroll
            for (int nf = 0; nf < 4; nf++) {
                int nloc = nf * 16 + (l & 15);
                float d = dnm - 2.f * acc[mfl][nf][r] + bnf[nloc];
                unsigned long long key = ((unsigned long long)ordf(d) << 32) | (unsigned)(n0 + nloc);
                if (key < best) best = key;
            }
            #pragma unroll
            for (int off = 1; off < 16; off <<= 1) {
                unsigned long long o = __shfl_xor(best, off);
                if (o < best) best = o;
            }
            if ((l & 15) == 0) atomicMin(&minkey[b * KKP + m], best);
        }
    }
}

// ---------------- K5: finalize ----------------
__global__ void finalize_kernel(const unsigned long long* __restrict__ minkey,
                                const int* __restrict__ kp,
                                float* __restrict__ out)
{
    int b = blockIdx.x;
    int k = threadIdx.x;
    unsigned long long key = minkey[b * KKP + k];
    unsigned n   = (unsigned)(key & 0xffffffffu);
    unsigned top = (unsigned)(key >> 32);
    unsigned fbits = (top & 0x80000000u) ? (top ^ 0x80000000u) : ~top;
    out[8 + b * KKP + k] = __uint_as_float(fbits);

    int idxA = kp[b * KKP + k];
    int rowA = idxA >> 7, colA = idxA & 127;
    int rowB = (int)(n >> 7), colB = (int)(n & 127);
    int drow = rowA - rowB, dcol = colA - colB;
    int code = (drow + 256) * 1024 + (dcol + 256);

    __shared__ int codes[KKP];
    __shared__ int keys[KKP];
    codes[k] = code;
    __syncthreads();
    int cnt = 0;
    for (int j = 0; j < KKP; j++) cnt += (codes[j] == code);
    keys[k] = cnt * 256 + (255 - k);
    __syncthreads();
    for (int s = 128; s; s >>= 1) {
        if (k < s) keys[k] = max(keys[k], keys[k + s]);
        __syncthreads();
    }
    if (k == 0) {
        int bestk = 255 - (keys[0] & 255);
        int bc = codes[bestk];
        int dr = bc / 1024 - 256, dc = bc % 1024 - 256;
        out[b * 2 + 0] = (float)dr;
        out[b * 2 + 1] = (float)dc;
    }
}

extern "C" void kernel_launch(void* const* d_in, const int* in_sizes, int n_in,
                              void* d_out, int out_size, void* d_ws, size_t ws_size,
                              hipStream_t stream) {
    const float* A  = (const float*)d_in[0];
    const float* Bf = (const float*)d_in[1];
    float* out = (float*)d_out;
    char* ws = (char*)d_ws;

    float* resp = (float*)ws;                                   // 256 KB
    int*   kp   = (int*)(ws + 262144);                          // 4 KB
    float* dn   = (float*)(ws + 266240);                        // 4 KB
    unsigned long long* minkey = (unsigned long long*)(ws + 270336); // 8 KB
    uint4* frag = (uint4*)(ws + 278528);                        // 2 MB
    float* part = (float*)(ws + 278528 + 2097152);              // 2 MB

    hipMemsetAsync(minkey, 0xFF, BDIM * KKP * sizeof(unsigned long long), stream);
    resp_part_kernel<<<BDIM * 8 * HWDIM / 256, 256, 0, stream>>>(A, part);
    resp_comb_kernel<<<BDIM * HWDIM / 256, 256, 0, stream>>>(part, resp);
    argmax_kernel<<<BDIM * KKP, 64, 0, stream>>>(resp, kp);
    convert_kernel<<<BDIM * 16, 256, 0, stream>>>(A, kp, frag, dn);
    dist_mfma_kernel<<<1024, 512, 0, stream>>>(frag, Bf, dn, minkey);
    finalize_kernel<<<BDIM, KKP, 0, stream>>>(minkey, kp, out);
}

// Round 12
// 113.667 us; speedup vs baseline: 1.6795x; 1.0312x over previous
//
#include <hip/hip_runtime.h>
#include <hip/hip_bf16.h>
#include <stdint.h>

#define BDIM 4
#define CDIM 512
#define HDIM 128
#define WDIM 128
#define HWDIM (HDIM*WDIM)
#define SADMP 16
#define BHW 8
#define KKP 256

using short8 = __attribute__((ext_vector_type(8))) short;
using f32x4  = __attribute__((ext_vector_type(4))) float;

// native HW convert for the hi term (RNE); lo term is rounding-agnostic
__device__ __forceinline__ unsigned short f2bf(float f) {
    union { __hip_bfloat16 h; unsigned short u; } cv;
    cv.h = __float2bfloat16(f);
    return cv.u;
}
__device__ __forceinline__ float bf2f(unsigned short h) {
    return __uint_as_float(((unsigned)h) << 16);
}
__device__ __forceinline__ unsigned int ordf(float f) {
    unsigned u = __float_as_uint(f);
    return (u & 0x80000000u) ? ~u : (u | 0x80000000u);
}
// writer-side LDS drain + raw barrier; no vmcnt drain (globals stay in flight)
__device__ __forceinline__ void step_barrier() {
    asm volatile("s_waitcnt lgkmcnt(0)" ::: "memory");
    __builtin_amdgcn_s_barrier();
}

// ---------------- K1: channel-chunk partial sums (8 chunks of 64) ----------------
__global__ void resp_part_kernel(const float* __restrict__ A, float* __restrict__ part) {
    int gid = blockIdx.x * blockDim.x + threadIdx.x;   // (b*8+cq)*HW + hw
    int hw = gid & (HWDIM - 1);
    int rest = gid >> 14;
    int b = rest >> 3, cq = rest & 7;
    const float* p = A + (size_t)b * CDIM * HWDIM + (size_t)(cq * 64) * HWDIM + hw;
    float s0 = 0.f, s1 = 0.f, s2 = 0.f, s3 = 0.f;
    #pragma unroll 4
    for (int c = 0; c < 64; c += 4) {
        s0 += p[(size_t)(c + 0) * HWDIM];
        s1 += p[(size_t)(c + 1) * HWDIM];
        s2 += p[(size_t)(c + 2) * HWDIM];
        s3 += p[(size_t)(c + 3) * HWDIM];
    }
    part[gid] = (s0 + s1) + (s2 + s3);
}

// ---------------- K2: per-window argmax, comb fused (ascending cq = identical FP) ----
__global__ void argmax_kernel(const float* __restrict__ part, int* __restrict__ kp) {
    int win = blockIdx.x;                 // b*K + k
    int b = win / KKP, k = win % KKP;
    int bi = k / SADMP, bj = k % SADMP;
    int l = threadIdx.x;                  // 0..63 == loc
    int r = l >> 3, c = l & 7;
    int h = bi * BHW + r, w = bj * BHW + c;
    const float* p = part + (size_t)(b * 8) * HWDIM + h * WDIM + w;
    float v = 0.f;
    #pragma unroll
    for (int cq = 0; cq < 8; cq++) v += p[(size_t)cq * HWDIM];
    int idx = l;
    #pragma unroll
    for (int off = 32; off; off >>= 1) {
        float ov = __shfl_down(v, off);
        int   oi = __shfl_down(idx, off);
        if (ov > v || (ov == v && oi < idx)) { v = ov; idx = oi; }
    }
    if (l == 0) {
        int row = bi * BHW + (idx >> 3);
        int col = bj * BHW + (idx & 7);
        kp[win] = row * WDIM + col;
    }
}

// ---------------- K3: gather + hi/lo convert into 16x16 MFMA A-frag order + dn ----
__global__ void convert_kernel(const float* __restrict__ A, const int* __restrict__ kp,
                               uint4* __restrict__ frag, float* __restrict__ dn) {
    int blk = blockIdx.x;                 // b*16 + mf
    int b = blk >> 4, mf = blk & 15;
    int t = threadIdx.x;                  // 0..255
    int l = t & 63, q0 = t >> 6;
    int ml = l & 15;
    int m  = mf * 16 + ml;
    int cg = (l >> 4) * 8;
    int idx = kp[b * KKP + m];
    const float* Ab = A + (size_t)b * CDIM * HWDIM + idx;
    float sq = 0.f;
    #pragma unroll
    for (int qq = 0; qq < 4; qq++) {
        int q = q0 * 4 + qq;
        unsigned hi[4], lo[4];
        #pragma unroll
        for (int jj = 0; jj < 4; jj++) {
            int c0 = q * 32 + cg + jj * 2;
            float v0 = Ab[(size_t)c0 * HWDIM];
            float v1 = Ab[(size_t)(c0 + 1) * HWDIM];
            sq = fmaf(v0, v0, sq);
            sq = fmaf(v1, v1, sq);
            unsigned short h0 = f2bf(v0), h1 = f2bf(v1);
            unsigned short g0 = f2bf(v0 - bf2f(h0)), g1 = f2bf(v1 - bf2f(h1));
            hi[jj] = (unsigned)h0 | ((unsigned)h1 << 16);
            lo[jj] = (unsigned)g0 | ((unsigned)g1 << 16);
        }
        frag[((size_t)b * 2 + 0) * 16384 + mf * 1024 + q * 64 + l] = make_uint4(hi[0], hi[1], hi[2], hi[3]);
        frag[((size_t)b * 2 + 1) * 16384 + mf * 1024 + q * 64 + l] = make_uint4(lo[0], lo[1], lo[2], lo[3]);
    }
    __shared__ float red[16][17];
    red[ml][(l >> 4) * 4 + q0] = sq;
    __syncthreads();
    if (t < 16) {
        float s = 0.f;
        #pragma unroll
        for (int i = 0; i < 16; i++) s += red[t][i];
        dn[b * KKP + mf * 16 + t] = s;
    }
}

// ---------------- K4: MFMA dist + argmin (r10 structure, validated 89us) ----------
// BM=256, BN=64, BK=64/step, 8 steps, 16x16x32, bf16 hi/lo 3-term.
// Fragment-order dbuf LDS (0 conflicts), ONE raw s_barrier/step.
// A-frags register-double-buffered via temps (aN*), committed after the
// merged 48-MFMA setprio cluster; fb 2 steps ahead; T1 batch-major swizzle.
__global__ __launch_bounds__(512) void dist_mfma_kernel(
    const uint4* __restrict__ fragA, const float* __restrict__ fb,
    const float* __restrict__ dn, unsigned long long* __restrict__ minkey)
{
    // T1: bijective XCD swizzle, batch-major (1024 blocks, 1024%8==0).
    const int u    = blockIdx.x;
    const int g    = (u & 7) * 128 + (u >> 3);
    const int b    = g >> 8;
    const int n0   = (g & 255) * 64;

    const int t  = threadIdx.x;
    const int l  = t & 63;
    const int w  = t >> 6;                // wave 0..7: rows w*32 .. w*32+31

    __shared__ char sb[2][16384];         // [buf][term:2][ch:2][nf:4][1024]
    __shared__ float bnp[8][64];
    __shared__ float bnf[64];
    __shared__ float dnl[256];

    if (t < 256) dnl[t] = dn[b * KKP + t];

    f32x4 acc[2][4] = {};                 // [mfl][nf]

    const int scol = t & 63;
    const int sw   = t >> 6;
    const int wbase = ((sw >> 2) << 12) + ((scol >> 4) << 10) + (((((sw & 3) << 4) + (scol & 15))) << 4);
    const float* fbp = fb + (size_t)b * CDIM * HWDIM + (size_t)(sw * 8) * HWDIM + n0 + scol;
    float bnacc = 0.f;

    const short8* fA = (const short8*)fragA;
    const size_t a0Hi = ((size_t)b * 2 + 0) * 16384 + (size_t)(w * 2 + 0) * 1024 + l;
    const size_t a1Hi = ((size_t)b * 2 + 0) * 16384 + (size_t)(w * 2 + 1) * 1024 + l;
    const size_t a0Lo = ((size_t)b * 2 + 1) * 16384 + (size_t)(w * 2 + 0) * 1024 + l;
    const size_t a1Lo = ((size_t)b * 2 + 1) * 16384 + (size_t)(w * 2 + 1) * 1024 + l;

    float v[8];
    // prologue: step0 fb -> buf0; step1 fb loads; step0 ch0 frags; barrier.
    #pragma unroll
    for (int i = 0; i < 8; i++) v[i] = fbp[(size_t)i * HWDIM];
    {
        unsigned hi[4], lo[4];
        #pragma unroll
        for (int jj = 0; jj < 4; jj++) {
            float v0 = v[jj * 2], v1 = v[jj * 2 + 1];
            bnacc = fmaf(v0, v0, bnacc);
            bnacc = fmaf(v1, v1, bnacc);
            unsigned short h0 = f2bf(v0), h1 = f2bf(v1);
            unsigned short g0 = f2bf(v0 - bf2f(h0)), g1 = f2bf(v1 - bf2f(h1));
            hi[jj] = (unsigned)h0 | ((unsigned)h1 << 16);
            lo[jj] = (unsigned)g0 | ((unsigned)g1 << 16);
        }
        *(uint4*)(&sb[0][wbase])        = make_uint4(hi[0], hi[1], hi[2], hi[3]);
        *(uint4*)(&sb[0][wbase + 8192]) = make_uint4(lo[0], lo[1], lo[2], lo[3]);
    }
    #pragma unroll
    for (int i = 0; i < 8; i++) v[i] = fbp[(size_t)(64 + i) * HWDIM];
    short8 aA0 = fA[a0Hi], aA1 = fA[a1Hi], aA2 = fA[a0Lo], aA3 = fA[a1Lo];
    step_barrier();

    for (int s = 0; s < 8; s++) {
        const int cur = s & 1;
        const char* rb = sb[cur];

        // staging: convert step s+1 -> buf^1; issue fb loads for s+2.
        if (s < 7) {
            unsigned hi[4], lo[4];
            #pragma unroll
            for (int jj = 0; jj < 4; jj++) {
                float v0 = v[jj * 2], v1 = v[jj * 2 + 1];
                bnacc = fmaf(v0, v0, bnacc);
                bnacc = fmaf(v1, v1, bnacc);
                unsigned short h0 = f2bf(v0), h1 = f2bf(v1);
                unsigned short g0 = f2bf(v0 - bf2f(h0)), g1 = f2bf(v1 - bf2f(h1));
                hi[jj] = (unsigned)h0 | ((unsigned)h1 << 16);
                lo[jj] = (unsigned)g0 | ((unsigned)g1 << 16);
            }
            char* wp = (char*)sb[cur ^ 1] + wbase;
            *(uint4*)(wp)        = make_uint4(hi[0], hi[1], hi[2], hi[3]);
            *(uint4*)(wp + 8192) = make_uint4(lo[0], lo[1], lo[2], lo[3]);
            if (s < 6) {
                #pragma unroll
                for (int i = 0; i < 8; i++)
                    v[i] = fbp[(size_t)((s + 2) * 64 + i) * HWDIM];
            }
        }

        // issue ch1 A-frag loads (land under the first 24 MFMAs)
        const size_t qB = (size_t)(s * 2 + 1) * 64;
        short8 aB0 = fA[a0Hi + qB];
        short8 aB1 = fA[a1Hi + qB];
        short8 aB2 = fA[a0Lo + qB];
        short8 aB3 = fA[a1Lo + qB];

        // issue NEXT-step ch0 A-frag loads into TEMPS (aA* still live below)
        short8 aN0 = aA0, aN1 = aA1, aN2 = aA2, aN3 = aA3;
        if (s < 7) {
            const size_t qN = (size_t)(s * 2 + 2) * 64;
            aN0 = fA[a0Hi + qN];
            aN1 = fA[a1Hi + qN];
            aN2 = fA[a0Lo + qN];
            aN3 = fA[a1Lo + qN];
        }

        // merged 48-MFMA cluster under raised priority (T5)
        {
            const char* rp0 = rb + l * 16;
            const char* rp1 = rb + 4096 + l * 16;
            __builtin_amdgcn_s_setprio(1);
            #pragma unroll
            for (int nf = 0; nf < 4; nf++) {
                short8 bh = *(const short8*)(rp0 + nf * 1024);
                short8 bl = *(const short8*)(rp0 + nf * 1024 + 8192);
                acc[0][nf] = __builtin_amdgcn_mfma_f32_16x16x32_bf16(aA0, bh, acc[0][nf], 0, 0, 0);
                acc[0][nf] = __builtin_amdgcn_mfma_f32_16x16x32_bf16(aA0, bl, acc[0][nf], 0, 0, 0);
                acc[0][nf] = __builtin_amdgcn_mfma_f32_16x16x32_bf16(aA2, bh, acc[0][nf], 0, 0, 0);
                acc[1][nf] = __builtin_amdgcn_mfma_f32_16x16x32_bf16(aA1, bh, acc[1][nf], 0, 0, 0);
                acc[1][nf] = __builtin_amdgcn_mfma_f32_16x16x32_bf16(aA1, bl, acc[1][nf], 0, 0, 0);
                acc[1][nf] = __builtin_amdgcn_mfma_f32_16x16x32_bf16(aA3, bh, acc[1][nf], 0, 0, 0);
            }
            #pragma unroll
            for (int nf = 0; nf < 4; nf++) {
                short8 bh = *(const short8*)(rp1 + nf * 1024);
                short8 bl = *(const short8*)(rp1 + nf * 1024 + 8192);
                acc[0][nf] = __builtin_amdgcn_mfma_f32_16x16x32_bf16(aB0, bh, acc[0][nf], 0, 0, 0);
                acc[0][nf] = __builtin_amdgcn_mfma_f32_16x16x32_bf16(aB0, bl, acc[0][nf], 0, 0, 0);
                acc[0][nf] = __builtin_amdgcn_mfma_f32_16x16x32_bf16(aB2, bh, acc[0][nf], 0, 0, 0);
                acc[1][nf] = __builtin_amdgcn_mfma_f32_16x16x32_bf16(aB1, bh, acc[1][nf], 0, 0, 0);
                acc[1][nf] = __builtin_amdgcn_mfma_f32_16x16x32_bf16(aB1, bl, acc[1][nf], 0, 0, 0);
                acc[1][nf] = __builtin_amdgcn_mfma_f32_16x16x32_bf16(aB3, bh, acc[1][nf], 0, 0, 0);
            }
            __builtin_amdgcn_s_setprio(0);
        }

        // commit A reg-dbuf for next step (loads stay in flight across barrier)
        aA0 = aN0; aA1 = aN1; aA2 = aN2; aA3 = aN3;
        if (s < 7) step_barrier();
    }

    // bn reduction
    bnp[sw][scol] = bnacc;
    __syncthreads();
    if (t < 64) {
        float s = 0.f;
        #pragma unroll
        for (int i = 0; i < 8; i++) s += bnp[i][t];
        bnf[t] = s;
    }
    __syncthreads();

    // epilogue: dist = dn - 2*cross + bn, packed argmin, atomicMin
    #pragma unroll
    for (int mfl = 0; mfl < 2; mfl++) {
        #pragma unroll
        for (int r = 0; r < 4; r++) {
            int m = w * 32 + mfl * 16 + (l >> 4) * 4 + r;
            float dnm = dnl[m];
            unsigned long long best = ~0ull;
            #pragma unroll
            for (int nf = 0; nf < 4; nf++) {
                int nloc = nf * 16 + (l & 15);
                float d = dnm - 2.f * acc[mfl][nf][r] + bnf[nloc];
                unsigned long long key = ((unsigned long long)ordf(d) << 32) | (unsigned)(n0 + nloc);
                if (key < best) best = key;
            }
            #pragma unroll
            for (int off = 1; off < 16; off <<= 1) {
                unsigned long long o = __shfl_xor(best, off);
                if (o < best) best = o;
            }
            if ((l & 15) == 0) atomicMin(&minkey[b * KKP + m], best);
        }
    }
}

// ---------------- K5: finalize ----------------
__global__ void finalize_kernel(const unsigned long long* __restrict__ minkey,
                                const int* __restrict__ kp,
                                float* __restrict__ out)
{
    int b = blockIdx.x;
    int k = threadIdx.x;
    unsigned long long key = minkey[b * KKP + k];
    unsigned n   = (unsigned)(key & 0xffffffffu);
    unsigned top = (unsigned)(key >> 32);
    unsigned fbits = (top & 0x80000000u) ? (top ^ 0x80000000u) : ~top;
    out[8 + b * KKP + k] = __uint_as_float(fbits);

    int idxA = kp[b * KKP + k];
    int rowA = idxA >> 7, colA = idxA & 127;
    int rowB = (int)(n >> 7), colB = (int)(n & 127);
    int drow = rowA - rowB, dcol = colA - colB;
    int code = (drow + 256) * 1024 + (dcol + 256);

    __shared__ int codes[KKP];
    __shared__ int keys[KKP];
    codes[k] = code;
    __syncthreads();
    int cnt = 0;
    for (int j = 0; j < KKP; j++) cnt += (codes[j] == code);
    keys[k] = cnt * 256 + (255 - k);
    __syncthreads();
    for (int s = 128; s; s >>= 1) {
        if (k < s) keys[k] = max(keys[k], keys[k + s]);
        __syncthreads();
    }
    if (k == 0) {
        int bestk = 255 - (keys[0] & 255);
        int bc = codes[bestk];
        int dr = bc / 1024 - 256, dc = bc % 1024 - 256;
        out[b * 2 + 0] = (float)dr;
        out[b * 2 + 1] = (float)dc;
    }
}

extern "C" void kernel_launch(void* const* d_in, const int* in_sizes, int n_in,
                              void* d_out, int out_size, void* d_ws, size_t ws_size,
                              hipStream_t stream) {
    const float* A  = (const float*)d_in[0];
    const float* Bf = (const float*)d_in[1];
    float* out = (float*)d_out;
    char* ws = (char*)d_ws;

    int*   kp   = (int*)(ws + 262144);                          // 4 KB
    float* dn   = (float*)(ws + 266240);                        // 4 KB
    unsigned long long* minkey = (unsigned long long*)(ws + 270336); // 8 KB
    uint4* frag = (uint4*)(ws + 278528);                        // 2 MB
    float* part = (float*)(ws + 278528 + 2097152);              // 2 MB

    hipMemsetAsync(minkey, 0xFF, BDIM * KKP * sizeof(unsigned long long), stream);
    resp_part_kernel<<<BDIM * 8 * HWDIM / 256, 256, 0, stream>>>(A, part);
    argmax_kernel<<<BDIM * KKP, 64, 0, stream>>>(part, kp);
    convert_kernel<<<BDIM * 16, 256, 0, stream>>>(A, kp, frag, dn);
    dist_mfma_kernel<<<1024, 512, 0, stream>>>(frag, Bf, dn, minkey);
    finalize_kernel<<<BDIM, KKP, 0, stream>>>(minkey, kp, out);
}